// Round 4
// baseline (294.449 us; speedup 1.0000x reference)
//
#include <hip/hip_runtime.h>
#include <math.h>

// Problem constants
#define TT   4096
#define NBB  32
#define NUU  64
#define NHH  256
#define HH   128
#define NYY  64
// Chunking: 512 chunks of 8 steps; carry hierarchy: 16 supers x 32 chunks
#define LCH  8
#define CCH  512
#define SEGN 16
#define CPS  32

#define PI_HALF 1.5707963267948966f

typedef float  f32x16 __attribute__((ext_vector_type(16)));
typedef __bf16 bf16x8 __attribute__((ext_vector_type(8)));
typedef __bf16 bf16x2 __attribute__((ext_vector_type(2)));
typedef unsigned int uint4v __attribute__((ext_vector_type(4)));

// MFMA 32x32 C/D layout: row = (r&3) + 8*(r>>2) + 4*(lane>>5), col = lane&31
__device__ inline int crow(int r, int lane) { return (r & 3) + 8 * (r >> 2) + 4 * (lane >> 5); }
__device__ inline bf16x8 ldfrag(const unsigned short* p) {
    return __builtin_bit_cast(bf16x8, *(const uint4v*)p);
}

// split a float into bf16 hi + bf16 lo (hi+lo ~ exact to 2^-17 rel)
#define CVT(v, H, L) { __bf16 _h = (__bf16)(v); H = _h; L = (__bf16)((v) - (float)_h); }

// lambda in fp32 with correctly-rounded transcendentals (double -> fp32)
__device__ inline void lam_f32(float xre, float xim, float& lr, float& li) {
    float th = PI_HALF * xim;
    float rf = (float)exp(-(double)fabsf(xre));
    float cf = (float)cos((double)th);
    float sf = (float)sin((double)th);
    lr = rf * cf; li = rf * sf;
}

// --- swizzled LDS index helpers (offsets in shorts, 16B chunk = 8 shorts) ---
// pass1 sU: row stride 136 shorts (+pad, round-2 proven layout) -- no swizzle.
// pass2 sU (32 rows x 128): chunk(4b) ^= row&15
__device__ inline int swzU1(int row, int so) {
    return row * 128 + ((((so >> 3) ^ row) & 15) << 3) + (so & 7);
}
// pass2 sX (32 rows x 512): low-5 of chunk ^= row, bit5 kept
__device__ inline int swzX1(int row, int so) {
    int chv = so >> 3;
    chv = (chv & 32) | ((chv ^ row) & 31);
    return row * 512 + (chv << 3) + (so & 7);
}

// ---------------------------------------------------------------------------
// Prep: x0 pairs; bf16 hi/lo split of B (plain) and W_x2y with interleaved K
// permute: Wp[y][2j] = W[y][j], Wp[y][2j+1] = W[y][j+128].
// ---------------------------------------------------------------------------
__global__ __launch_bounds__(256) void k_prep(
    const float* __restrict__ B, const float* __restrict__ W,
    const float* __restrict__ y0, const float* __restrict__ Wy2x,
    const float* __restrict__ by2x,
    unsigned short* __restrict__ Bph, unsigned short* __restrict__ Bpl,
    unsigned short* __restrict__ Wph, unsigned short* __restrict__ Wpl,
    float2* __restrict__ x0p)
{
    int bx = blockIdx.x, tid = threadIdx.x;
    if (bx < 32) {
        if (tid < HH) {
            int b = bx, ch = tid;
            float xr = by2x[ch], xi = by2x[ch + HH];
            for (int y = 0; y < NYY; ++y) {
                float v = y0[b * NYY + y];
                xr += v * Wy2x[ch * NYY + y];
                xi += v * Wy2x[(ch + HH) * NYY + y];
            }
            x0p[b * HH + ch] = make_float2(xr, xi);
        }
    } else {
        int i = (bx - 32) * 256 + tid;            // 0..16383
        float bv = B[i];
        __bf16 bh = (__bf16)bv;
        Bph[i] = __builtin_bit_cast(unsigned short, bh);
        Bpl[i] = __builtin_bit_cast(unsigned short, (__bf16)(bv - (float)bh));
        int y = i >> 8, kidx = i & 255;
        float wv = W[y * NHH + (kidx & 1) * HH + (kidx >> 1)];
        __bf16 wh = (__bf16)wv;
        Wph[i] = __builtin_bit_cast(unsigned short, wh);
        Wpl[i] = __builtin_bit_cast(unsigned short, (__bf16)(wv - (float)wh));
    }
}

// ---------------------------------------------------------------------------
// Pass 1: per-chunk (L=8) local end state E_c. Round-2 proven structure
// (dbuf sU, reg prefetch, hoisted bf) with launch_bounds(256,2):
// total reg demand ~230 <= 256 -> 2 blocks/CU, no scratch spill.
// ---------------------------------------------------------------------------
__global__ __launch_bounds__(256, 2) void k_pass1(
    const float* __restrict__ U,
    const unsigned short* __restrict__ Bph, const unsigned short* __restrict__ Bpl,
    const float* __restrict__ lre, const float* __restrict__ lim,
    float2* __restrict__ E)
{
    __shared__ __align__(16) unsigned short sU[2][64 * 136];   // 2 x 17.4 KB

    const int tid = threadIdx.x, w = tid >> 6, lane = tid & 63;
    const int l31 = lane & 31, kh = lane >> 5;
    const int c = blockIdx.x;
    const int ch = w * 32 + l31;

    float lr, li; lam_f32(lre[ch], lim[ch], lr, li);

    bf16x8 bfh[2][4], bfl[2][4];
#pragma unroll
    for (int nt = 0; nt < 2; ++nt)
#pragma unroll
        for (int kk = 0; kk < 4; ++kk) {
            bfh[nt][kk] = ldfrag(&Bph[(size_t)(nt * HH + ch) * NUU + kk * 16 + kh * 8]);
            bfl[nt][kk] = ldfrag(&Bpl[(size_t)(nt * HH + ch) * NUU + kk * 16 + kh * 8]);
        }

    float zr[16], zi[16];
#pragma unroll
    for (int r = 0; r < 16; ++r) { zr[r] = 0.f; zi[r] = 0.f; }

    const int srow = tid >> 2, sus = (tid & 3) * 16;
    const int sb = srow & 31, stoff = srow >> 5;
    const float* ubase = U + (size_t)sb * NUU + sus;

    float4 f0, f1, f2, f3;
    {
        const float4* sp = (const float4*)(ubase + (size_t)(c * LCH + stoff) * (NBB * NUU));
        f0 = sp[0]; f1 = sp[1]; f2 = sp[2]; f3 = sp[3];
    }

    for (int sub = 0; sub < 4; ++sub) {
        unsigned short* su = &sU[sub & 1][0];
        {
            bf16x8 h0, h1, l0, l1;
            CVT(f0.x, h0[0], l0[0]); CVT(f0.y, h0[1], l0[1]); CVT(f0.z, h0[2], l0[2]); CVT(f0.w, h0[3], l0[3]);
            CVT(f1.x, h0[4], l0[4]); CVT(f1.y, h0[5], l0[5]); CVT(f1.z, h0[6], l0[6]); CVT(f1.w, h0[7], l0[7]);
            CVT(f2.x, h1[0], l1[0]); CVT(f2.y, h1[1], l1[1]); CVT(f2.z, h1[2], l1[2]); CVT(f2.w, h1[3], l1[3]);
            CVT(f3.x, h1[4], l1[4]); CVT(f3.y, h1[5], l1[5]); CVT(f3.z, h1[6], l1[6]); CVT(f3.w, h1[7], l1[7]);
            *(bf16x8*)&su[srow * 136 + sus]          = h0;
            *(bf16x8*)&su[srow * 136 + sus + 8]      = h1;
            *(bf16x8*)&su[srow * 136 + 64 + sus]     = l0;
            *(bf16x8*)&su[srow * 136 + 64 + sus + 8] = l1;
        }
        __syncthreads();

        if (sub < 3) {
            const float4* sp = (const float4*)(ubase + (size_t)(c * LCH + (sub + 1) * 2 + stoff) * (NBB * NUU));
            f0 = sp[0]; f1 = sp[1]; f2 = sp[2]; f3 = sp[3];
        }

        f32x16 acc[2][2];
#pragma unroll
        for (int mt = 0; mt < 2; ++mt)
#pragma unroll
            for (int nt = 0; nt < 2; ++nt)
#pragma unroll
                for (int r = 0; r < 16; ++r) acc[mt][nt][r] = 0.f;

#pragma unroll
        for (int kk = 0; kk < 4; ++kk) {
            bf16x8 a0h = ldfrag(&su[(l31)      * 136 + kk * 16 + kh * 8]);
            bf16x8 a1h = ldfrag(&su[(32 + l31) * 136 + kk * 16 + kh * 8]);
            bf16x8 a0l = ldfrag(&su[(l31)      * 136 + 64 + kk * 16 + kh * 8]);
            bf16x8 a1l = ldfrag(&su[(32 + l31) * 136 + 64 + kk * 16 + kh * 8]);
            acc[0][0] = __builtin_amdgcn_mfma_f32_32x32x16_bf16(a0h, bfh[0][kk], acc[0][0], 0, 0, 0);
            acc[0][1] = __builtin_amdgcn_mfma_f32_32x32x16_bf16(a0h, bfh[1][kk], acc[0][1], 0, 0, 0);
            acc[1][0] = __builtin_amdgcn_mfma_f32_32x32x16_bf16(a1h, bfh[0][kk], acc[1][0], 0, 0, 0);
            acc[1][1] = __builtin_amdgcn_mfma_f32_32x32x16_bf16(a1h, bfh[1][kk], acc[1][1], 0, 0, 0);
            acc[0][0] = __builtin_amdgcn_mfma_f32_32x32x16_bf16(a0l, bfh[0][kk], acc[0][0], 0, 0, 0);
            acc[0][1] = __builtin_amdgcn_mfma_f32_32x32x16_bf16(a0l, bfh[1][kk], acc[0][1], 0, 0, 0);
            acc[1][0] = __builtin_amdgcn_mfma_f32_32x32x16_bf16(a1l, bfh[0][kk], acc[1][0], 0, 0, 0);
            acc[1][1] = __builtin_amdgcn_mfma_f32_32x32x16_bf16(a1l, bfh[1][kk], acc[1][1], 0, 0, 0);
            acc[0][0] = __builtin_amdgcn_mfma_f32_32x32x16_bf16(a0h, bfl[0][kk], acc[0][0], 0, 0, 0);
            acc[0][1] = __builtin_amdgcn_mfma_f32_32x32x16_bf16(a0h, bfl[1][kk], acc[0][1], 0, 0, 0);
            acc[1][0] = __builtin_amdgcn_mfma_f32_32x32x16_bf16(a1h, bfl[0][kk], acc[1][0], 0, 0, 0);
            acc[1][1] = __builtin_amdgcn_mfma_f32_32x32x16_bf16(a1h, bfl[1][kk], acc[1][1], 0, 0, 0);
        }

#pragma unroll
        for (int mt = 0; mt < 2; ++mt)
#pragma unroll
            for (int r = 0; r < 16; ++r) {
                float t0 = fmaf(lr, zr[r], acc[mt][0][r]); t0 = fmaf(-li, zi[r], t0);
                float t1 = fmaf(li, zr[r], acc[mt][1][r]); t1 = fmaf(lr, zi[r], t1);
                zr[r] = t0; zi[r] = t1;
            }
        // no trailing barrier: next sub writes the other buffer
    }

#pragma unroll
    for (int r = 0; r < 16; ++r)
        E[(size_t)c * 4096 + crow(r, lane) * HH + ch] = make_float2(zr[r], zi[r]);
}

// ---------------------------------------------------------------------------
// Carry hierarchy (unchanged).
// ---------------------------------------------------------------------------
__global__ __launch_bounds__(256) void k_cseg(
    const float* __restrict__ lre, const float* __restrict__ lim,
    const float2* __restrict__ E, float2* __restrict__ Esup)
{
    int g = blockIdx.x * 256 + threadIdx.x;
    int chain = g & 4095, seg = g >> 12, ch = chain & 127;
    float lrf, lif; lam_f32(lre[ch], lim[ch], lrf, lif);
    double pr = (double)lrf, pi = (double)lif;
#pragma unroll
    for (int s = 0; s < 3; ++s) { double nr = pr*pr - pi*pi, ni = 2.0*pr*pi; pr = nr; pi = ni; } // lambda^8
    double sr = 0.0, si = 0.0;
#pragma unroll 8
    for (int j = 0; j < CPS; ++j) {
        float2 e = E[((size_t)seg * CPS + j) * 4096 + chain];
        double nr = pr * sr - pi * si + (double)e.x;
        double ni = pi * sr + pr * si + (double)e.y;
        sr = nr; si = ni;
    }
    Esup[(size_t)seg * 4096 + chain] = make_float2((float)sr, (float)si);
}

__global__ __launch_bounds__(256) void k_csup(
    const float* __restrict__ lre, const float* __restrict__ lim,
    const float2* __restrict__ x0p, const float2* __restrict__ Esup,
    float2* __restrict__ CarrySup)
{
    int chain = blockIdx.x * 256 + threadIdx.x;   // grid 16 -> 0..4095
    int ch = chain & 127;
    float lrf, lif; lam_f32(lre[ch], lim[ch], lrf, lif);
    double pr = (double)lrf, pi = (double)lif;
#pragma unroll
    for (int s = 0; s < 8; ++s) { double nr = pr*pr - pi*pi, ni = 2.0*pr*pi; pr = nr; pi = ni; } // lambda^256
    float2 c0 = x0p[chain];
    double cr = (double)c0.x, ci = (double)c0.y;
#pragma unroll
    for (int s = 0; s < SEGN; ++s) {
        CarrySup[(size_t)s * 4096 + chain] = make_float2((float)cr, (float)ci);
        float2 e = Esup[(size_t)s * 4096 + chain];
        double nr = pr * cr - pi * ci + (double)e.x;
        double ni = pi * cr + pr * ci + (double)e.y;
        cr = nr; ci = ni;
    }
}

__global__ __launch_bounds__(256) void k_cexp(
    const float* __restrict__ lre, const float* __restrict__ lim,
    const float2* __restrict__ E, const float2* __restrict__ CarrySup,
    float2* __restrict__ Carry)
{
    int g = blockIdx.x * 256 + threadIdx.x;
    int chain = g & 4095, seg = g >> 12, ch = chain & 127;
    float lrf, lif; lam_f32(lre[ch], lim[ch], lrf, lif);
    double pr = (double)lrf, pi = (double)lif;
#pragma unroll
    for (int s = 0; s < 3; ++s) { double nr = pr*pr - pi*pi, ni = 2.0*pr*pi; pr = nr; pi = ni; } // lambda^8
    float2 cc = CarrySup[(size_t)seg * 4096 + chain];
    double cr = (double)cc.x, ci = (double)cc.y;
#pragma unroll 8
    for (int j = 0; j < CPS; ++j) {
        size_t idx = ((size_t)seg * CPS + j) * 4096 + chain;
        Carry[idx] = make_float2((float)cr, (float)ci);
        float2 e = E[idx];
        double nr = pr * cr - pi * ci + (double)e.x;
        double ni = pi * cr + pr * ci + (double)e.y;
        cr = nr; ci = ni;
    }
}

// ---------------------------------------------------------------------------
// Pass 2 (v4): 1-timestep subs to fit 2 blocks/CU.
// Per t: [cvt+write sU(t); out-GEMM(t-1) K-split partials; odd waves ->
//        sRed] bar [even waves: add partner + store Y(t-1); prefetch U(t+1);
//        Bu MFMA(t); scan; dump sX(t)] bar.
// Wave roles: scan: ch = w*32+l31. out-GEMM: nt_o = w>>1 (y-half),
// kh2 = w&1 (K-half). LDS = 8 + 32 + 8 = 48 KB; regs ~208 total -> (256,2).
// ---------------------------------------------------------------------------
__global__ __launch_bounds__(256, 2) void k_pass2(
    const float* __restrict__ U,
    const unsigned short* __restrict__ Bph, const unsigned short* __restrict__ Bpl,
    const unsigned short* __restrict__ Wph, const unsigned short* __restrict__ Wpl,
    const float* __restrict__ lre, const float* __restrict__ lim,
    const float* __restrict__ bx2y,
    const float2* __restrict__ Carry, float* __restrict__ Y)
{
    __shared__ __align__(16) unsigned short sU[32 * 128];   // 8 KB, swizzled
    __shared__ __align__(16) unsigned short sX[32 * 512];   // 32 KB, swizzled
    __shared__ float sRed[2][32 * 32];                      // 8 KB

    const int tid = threadIdx.x, w = tid >> 6, lane = tid & 63;
    const int l31 = lane & 31, kh = lane >> 5;
    const int c = blockIdx.x;
    const int ch = w * 32 + l31;           // scan channel
    const int nt_o = w >> 1, kh2 = w & 1;  // out-GEMM role (y-half, K-half)

    float lr, li; lam_f32(lre[ch], lim[ch], lr, li);
    float ybias = bx2y[nt_o * 32 + l31];

    // hoisted B fragments (scan role)
    bf16x8 bfh[2][4], bfl[2][4];
#pragma unroll
    for (int nt = 0; nt < 2; ++nt)
#pragma unroll
        for (int kk = 0; kk < 4; ++kk) {
            bfh[nt][kk] = ldfrag(&Bph[(size_t)(nt * HH + ch) * NUU + kk * 16 + kh * 8]);
            bfl[nt][kk] = ldfrag(&Bpl[(size_t)(nt * HH + ch) * NUU + kk * 16 + kh * 8]);
        }

    // hoisted W fragments: only this wave's K-half (32 regs)
    bf16x8 wfh[8], wfl[8];
#pragma unroll
    for (int kkl = 0; kkl < 8; ++kkl) {
        size_t off = (size_t)(nt_o * 32 + l31) * NHH + (kh2 * 8 + kkl) * 16 + kh * 8;
        wfh[kkl] = ldfrag(&Wph[off]);
        wfl[kkl] = ldfrag(&Wpl[off]);
    }

    // seed from Carry
    float zr[16], zi[16];
#pragma unroll
    for (int r = 0; r < 16; ++r) {
        float2 v = Carry[(size_t)c * 4096 + crow(r, lane) * HH + ch];
        zr[r] = v.x; zi[r] = v.y;
    }

    // U staging: 32 rows x 64 u per t; thread -> 8 floats
    const int srow = tid >> 3, sus = (tid & 7) * 8;
    const float* ubase = U + ((size_t)(c * LCH) * NBB + srow) * NUU + sus;

    float4 f0, f1;
    { const float4* sp = (const float4*)ubase; f0 = sp[0]; f1 = sp[1]; }

    for (int t = 0; t < LCH; ++t) {
        // cvt + write sU(t)
        {
            bf16x8 h, l;
            CVT(f0.x, h[0], l[0]); CVT(f0.y, h[1], l[1]); CVT(f0.z, h[2], l[2]); CVT(f0.w, h[3], l[3]);
            CVT(f1.x, h[4], l[4]); CVT(f1.y, h[5], l[5]); CVT(f1.z, h[6], l[6]); CVT(f1.w, h[7], l[7]);
            *(bf16x8*)&sU[swzU1(srow, sus)]      = h;
            *(bf16x8*)&sU[swzU1(srow, 64 + sus)] = l;
        }

        f32x16 ya0, ya1;
        if (t > 0) {   // out-GEMM partial for t-1 (this wave's K-half)
#pragma unroll
            for (int r = 0; r < 16; ++r) { ya0[r] = 0.f; ya1[r] = 0.f; }
#pragma unroll
            for (int kkl = 0; kkl < 8; ++kkl) {
                int kkg = kh2 * 8 + kkl;
                bf16x8 xah = ldfrag(&sX[swzX1(l31, kkg * 16 + kh * 8)]);
                bf16x8 xal = ldfrag(&sX[swzX1(l31, 256 + kkg * 16 + kh * 8)]);
                ya0 = __builtin_amdgcn_mfma_f32_32x32x16_bf16(xah, wfh[kkl], ya0, 0, 0, 0);
                ya1 = __builtin_amdgcn_mfma_f32_32x32x16_bf16(xal, wfh[kkl], ya1, 0, 0, 0);
                ya1 = __builtin_amdgcn_mfma_f32_32x32x16_bf16(xah, wfl[kkl], ya1, 0, 0, 0);
            }
            if (kh2 == 1) {
#pragma unroll
                for (int r = 0; r < 16; ++r)
                    sRed[nt_o][crow(r, lane) * 32 + l31] = ya0[r] + ya1[r];
            }
        }
        __syncthreads();

        if (t > 0 && kh2 == 0) {   // combine + store Y(t-1)
            int tt = c * LCH + t - 1;
#pragma unroll
            for (int r = 0; r < 16; ++r)
                Y[((size_t)tt * NBB + crow(r, lane)) * NYY + nt_o * 32 + l31] =
                    ya0[r] + ya1[r] + sRed[nt_o][crow(r, lane) * 32 + l31] + ybias;
        }

        if (t < LCH - 1) {   // prefetch U(t+1), hides under Bu MFMA
            const float4* sp = (const float4*)(ubase + (size_t)(t + 1) * (NBB * NUU));
            f0 = sp[0]; f1 = sp[1];
        }

        // Bu MFMA (split 3-term, M=32)
        f32x16 acc0, acc1;
#pragma unroll
        for (int r = 0; r < 16; ++r) { acc0[r] = 0.f; acc1[r] = 0.f; }
#pragma unroll
        for (int kk = 0; kk < 4; ++kk) {
            bf16x8 a0h = ldfrag(&sU[swzU1(l31, kk * 16 + kh * 8)]);
            bf16x8 a0l = ldfrag(&sU[swzU1(l31, 64 + kk * 16 + kh * 8)]);
            acc0 = __builtin_amdgcn_mfma_f32_32x32x16_bf16(a0h, bfh[0][kk], acc0, 0, 0, 0);
            acc1 = __builtin_amdgcn_mfma_f32_32x32x16_bf16(a0h, bfh[1][kk], acc1, 0, 0, 0);
            acc0 = __builtin_amdgcn_mfma_f32_32x32x16_bf16(a0l, bfh[0][kk], acc0, 0, 0, 0);
            acc1 = __builtin_amdgcn_mfma_f32_32x32x16_bf16(a0l, bfh[1][kk], acc1, 0, 0, 0);
            acc0 = __builtin_amdgcn_mfma_f32_32x32x16_bf16(a0h, bfl[0][kk], acc0, 0, 0, 0);
            acc1 = __builtin_amdgcn_mfma_f32_32x32x16_bf16(a0h, bfl[1][kk], acc1, 0, 0, 0);
        }

        // scan step + split hi/lo dump into sX
#pragma unroll
        for (int r = 0; r < 16; ++r) {
            float t0 = fmaf(lr, zr[r], acc0[r]); t0 = fmaf(-li, zi[r], t0);
            float t1 = fmaf(li, zr[r], acc1[r]); t1 = fmaf(lr, zi[r], t1);
            zr[r] = t0; zi[r] = t1;
            bf16x2 hv, lv;
            { __bf16 _h = (__bf16)t0; hv[0] = _h; lv[0] = (__bf16)(t0 - (float)_h); }
            { __bf16 _h = (__bf16)t1; hv[1] = _h; lv[1] = (__bf16)(t1 - (float)_h); }
            int row = crow(r, lane);
            *(bf16x2*)&sX[swzX1(row, w * 64 + 2 * l31)]       = hv;
            *(bf16x2*)&sX[swzX1(row, 256 + w * 64 + 2 * l31)] = lv;
        }
        __syncthreads();
    }

    // drain: out-GEMM for t = LCH-1
    {
        f32x16 ya0, ya1;
#pragma unroll
        for (int r = 0; r < 16; ++r) { ya0[r] = 0.f; ya1[r] = 0.f; }
#pragma unroll
        for (int kkl = 0; kkl < 8; ++kkl) {
            int kkg = kh2 * 8 + kkl;
            bf16x8 xah = ldfrag(&sX[swzX1(l31, kkg * 16 + kh * 8)]);
            bf16x8 xal = ldfrag(&sX[swzX1(l31, 256 + kkg * 16 + kh * 8)]);
            ya0 = __builtin_amdgcn_mfma_f32_32x32x16_bf16(xah, wfh[kkl], ya0, 0, 0, 0);
            ya1 = __builtin_amdgcn_mfma_f32_32x32x16_bf16(xal, wfh[kkl], ya1, 0, 0, 0);
            ya1 = __builtin_amdgcn_mfma_f32_32x32x16_bf16(xah, wfl[kkl], ya1, 0, 0, 0);
        }
        if (kh2 == 1) {
#pragma unroll
            for (int r = 0; r < 16; ++r)
                sRed[nt_o][crow(r, lane) * 32 + l31] = ya0[r] + ya1[r];
        }
        __syncthreads();
        if (kh2 == 0) {
            int tt = c * LCH + LCH - 1;
#pragma unroll
            for (int r = 0; r < 16; ++r)
                Y[((size_t)tt * NBB + crow(r, lane)) * NYY + nt_o * 32 + l31] =
                    ya0[r] + ya1[r] + sRed[nt_o][crow(r, lane) * 32 + l31] + ybias;
        }
    }
}

// ---------------------------------------------------------------------------
extern "C" void kernel_launch(void* const* d_in, const int* in_sizes, int n_in,
                              void* d_out, int out_size, void* d_ws, size_t ws_size,
                              hipStream_t stream) {
    const float* y0    = (const float*)d_in[0];
    const float* U     = (const float*)d_in[1];
    const float* lre   = (const float*)d_in[2];
    const float* lim   = (const float*)d_in[3];
    const float* B     = (const float*)d_in[4];
    const float* W_y2x = (const float*)d_in[5];
    const float* b_y2x = (const float*)d_in[6];
    const float* W_x2y = (const float*)d_in[7];
    const float* b_x2y = (const float*)d_in[8];
    float* Y = (float*)d_out;

    char* p = (char*)d_ws;
    float2* E        = (float2*)p; p += (size_t)CCH * 4096 * sizeof(float2);   // 16.8 MB
    float2* Carry    = (float2*)p; p += (size_t)CCH * 4096 * sizeof(float2);   // 16.8 MB
    float2* Esup     = (float2*)p; p += (size_t)SEGN * 4096 * sizeof(float2);  // 512 KB
    float2* CarrySup = (float2*)p; p += (size_t)SEGN * 4096 * sizeof(float2);  // 512 KB
    float2* x0p      = (float2*)p; p += (size_t)4096 * sizeof(float2);         // 32 KB
    unsigned short* Bph = (unsigned short*)p; p += 16384 * sizeof(unsigned short);
    unsigned short* Bpl = (unsigned short*)p; p += 16384 * sizeof(unsigned short);
    unsigned short* Wph = (unsigned short*)p; p += 16384 * sizeof(unsigned short);
    unsigned short* Wpl = (unsigned short*)p; p += 16384 * sizeof(unsigned short);

    k_prep <<<dim3(96),  dim3(256), 0, stream>>>(B, W_x2y, y0, W_y2x, b_y2x, Bph, Bpl, Wph, Wpl, x0p);
    k_pass1<<<dim3(CCH), dim3(256), 0, stream>>>(U, Bph, Bpl, lre, lim, E);
    k_cseg <<<dim3(256), dim3(256), 0, stream>>>(lre, lim, E, Esup);
    k_csup <<<dim3(16),  dim3(256), 0, stream>>>(lre, lim, x0p, Esup, CarrySup);
    k_cexp <<<dim3(256), dim3(256), 0, stream>>>(lre, lim, E, CarrySup, Carry);
    k_pass2<<<dim3(CCH), dim3(256), 0, stream>>>(U, Bph, Bpl, Wph, Wpl, lre, lim, b_x2y, Carry, Y);
}

// Round 5
// 196.513 us; speedup vs baseline: 1.4984x; 1.4984x over previous
//
#include <hip/hip_runtime.h>
#include <math.h>

// Problem constants
#define TT   4096
#define NBB  32
#define NUU  64
#define NHH  256
#define HH   128
#define NYY  64
// Chunking: 512 chunks of 8 steps; carry hierarchy: 16 supers x 32 chunks
#define LCH  8
#define CCH  512
#define SEGN 16
#define CPS  32

#define PI_HALF 1.5707963267948966f

typedef float  f32x16 __attribute__((ext_vector_type(16)));
typedef __bf16 bf16x8 __attribute__((ext_vector_type(8)));
typedef __bf16 bf16x2 __attribute__((ext_vector_type(2)));
typedef unsigned int uint4v __attribute__((ext_vector_type(4)));

// MFMA 32x32 C/D layout: row = (r&3) + 8*(r>>2) + 4*(lane>>5), col = lane&31
__device__ inline int crow(int r, int lane) { return (r & 3) + 8 * (r >> 2) + 4 * (lane >> 5); }
__device__ inline bf16x8 ldfrag(const unsigned short* p) {
    return __builtin_bit_cast(bf16x8, *(const uint4v*)p);
}

// split a float into bf16 hi + bf16 lo (hi+lo ~ exact to 2^-17 rel)
#define CVT(v, H, L) { __bf16 _h = (__bf16)(v); H = _h; L = (__bf16)((v) - (float)_h); }

// lambda in fp32 with correctly-rounded transcendentals (double -> fp32)
__device__ inline void lam_f32(float xre, float xim, float& lr, float& li) {
    float th = PI_HALF * xim;
    float rf = (float)exp(-(double)fabsf(xre));
    float cf = (float)cos((double)th);
    float sf = (float)sin((double)th);
    lr = rf * cf; li = rf * sf;
}

// stage 16 fp32 (f0..f3) as split-bf16 into a 64x136-short padded tile row
#define STAGE136(DST, SROW, SUS) { \
    bf16x8 h0, h1, l0, l1; \
    CVT(f0.x, h0[0], l0[0]); CVT(f0.y, h0[1], l0[1]); CVT(f0.z, h0[2], l0[2]); CVT(f0.w, h0[3], l0[3]); \
    CVT(f1.x, h0[4], l0[4]); CVT(f1.y, h0[5], l0[5]); CVT(f1.z, h0[6], l0[6]); CVT(f1.w, h0[7], l0[7]); \
    CVT(f2.x, h1[0], l1[0]); CVT(f2.y, h1[1], l1[1]); CVT(f2.z, h1[2], l1[2]); CVT(f2.w, h1[3], l1[3]); \
    CVT(f3.x, h1[4], l1[4]); CVT(f3.y, h1[5], l1[5]); CVT(f3.z, h1[6], l1[6]); CVT(f3.w, h1[7], l1[7]); \
    *(bf16x8*)&DST[(SROW) * 136 + (SUS)]          = h0; \
    *(bf16x8*)&DST[(SROW) * 136 + (SUS) + 8]      = h1; \
    *(bf16x8*)&DST[(SROW) * 136 + 64 + (SUS)]     = l0; \
    *(bf16x8*)&DST[(SROW) * 136 + 64 + (SUS) + 8] = l1; }

// ---------------------------------------------------------------------------
// Prep: x0 pairs; bf16 hi/lo split of B (plain) and W_x2y with interleaved K
// permute: Wp[y][2j] = W[y][j], Wp[y][2j+1] = W[y][j+128].
// ---------------------------------------------------------------------------
__global__ __launch_bounds__(256) void k_prep(
    const float* __restrict__ B, const float* __restrict__ W,
    const float* __restrict__ y0, const float* __restrict__ Wy2x,
    const float* __restrict__ by2x,
    unsigned short* __restrict__ Bph, unsigned short* __restrict__ Bpl,
    unsigned short* __restrict__ Wph, unsigned short* __restrict__ Wpl,
    float2* __restrict__ x0p)
{
    int bx = blockIdx.x, tid = threadIdx.x;
    if (bx < 32) {
        if (tid < HH) {
            int b = bx, ch = tid;
            float xr = by2x[ch], xi = by2x[ch + HH];
            for (int y = 0; y < NYY; ++y) {
                float v = y0[b * NYY + y];
                xr += v * Wy2x[ch * NYY + y];
                xi += v * Wy2x[(ch + HH) * NYY + y];
            }
            x0p[b * HH + ch] = make_float2(xr, xi);
        }
    } else {
        int i = (bx - 32) * 256 + tid;            // 0..16383
        float bv = B[i];
        __bf16 bh = (__bf16)bv;
        Bph[i] = __builtin_bit_cast(unsigned short, bh);
        Bpl[i] = __builtin_bit_cast(unsigned short, (__bf16)(bv - (float)bh));
        int y = i >> 8, kidx = i & 255;
        float wv = W[y * NHH + (kidx & 1) * HH + (kidx >> 1)];
        __bf16 wh = (__bf16)wv;
        Wph[i] = __builtin_bit_cast(unsigned short, wh);
        Wpl[i] = __builtin_bit_cast(unsigned short, (__bf16)(wv - (float)wh));
    }
}

// ---------------------------------------------------------------------------
// Pass 1 (v5): 512 threads, role-split. Waves 0-3 compute (Bu MFMA + scan),
// waves 4-7 stage (U load + CVT + ds_write, double-buffered sU).
// One uniform barrier per sub. Per-wave regs ~200 -> 2 waves/SIMD, no cap.
// ---------------------------------------------------------------------------
__global__ __launch_bounds__(512) void k_pass1(
    const float* __restrict__ U,
    const unsigned short* __restrict__ Bph, const unsigned short* __restrict__ Bpl,
    const float* __restrict__ lre, const float* __restrict__ lim,
    float2* __restrict__ E)
{
    __shared__ __align__(16) unsigned short sU[2][64 * 136];   // 2 x 17.4 KB

    const int tid = threadIdx.x, w = tid >> 6, lane = tid & 63;
    const int l31 = lane & 31, kh = lane >> 5;
    const int c = blockIdx.x;
    const bool comp = (w < 4);
    const int ch = (w & 3) * 32 + l31;

    float lr = 0.f, li = 0.f;
    bf16x8 bfh[2][4], bfl[2][4];
    float zr[16], zi[16];
    if (comp) {
        lam_f32(lre[ch], lim[ch], lr, li);
#pragma unroll
        for (int nt = 0; nt < 2; ++nt)
#pragma unroll
            for (int kk = 0; kk < 4; ++kk) {
                bfh[nt][kk] = ldfrag(&Bph[(size_t)(nt * HH + ch) * NUU + kk * 16 + kh * 8]);
                bfl[nt][kk] = ldfrag(&Bpl[(size_t)(nt * HH + ch) * NUU + kk * 16 + kh * 8]);
            }
#pragma unroll
        for (int r = 0; r < 16; ++r) { zr[r] = 0.f; zi[r] = 0.f; }
    }

    // staging role (waves 4-7)
    const int tid2 = tid & 255;
    const int srow = tid2 >> 2, sus = (tid2 & 3) * 16;
    const int sb = srow & 31, stoff = srow >> 5;
    const float* ubase = U + (size_t)sb * NUU + sus;
    float4 f0, f1, f2, f3;

    if (!comp) {
        const float4* sp = (const float4*)(ubase + (size_t)(c * LCH + stoff) * (NBB * NUU));
        f0 = sp[0]; f1 = sp[1]; f2 = sp[2]; f3 = sp[3];
        STAGE136(sU[0], srow, sus);
        sp = (const float4*)(ubase + (size_t)(c * LCH + 2 + stoff) * (NBB * NUU));
        f0 = sp[0]; f1 = sp[1]; f2 = sp[2]; f3 = sp[3];
    }
    __syncthreads();

    for (int sub = 0; sub < 4; ++sub) {
        if (comp) {
            const unsigned short* su = &sU[sub & 1][0];
            f32x16 acc[2][2];
#pragma unroll
            for (int mt = 0; mt < 2; ++mt)
#pragma unroll
                for (int nt = 0; nt < 2; ++nt)
#pragma unroll
                    for (int r = 0; r < 16; ++r) acc[mt][nt][r] = 0.f;
#pragma unroll
            for (int kk = 0; kk < 4; ++kk) {
                bf16x8 a0h = ldfrag(&su[(l31)      * 136 + kk * 16 + kh * 8]);
                bf16x8 a1h = ldfrag(&su[(32 + l31) * 136 + kk * 16 + kh * 8]);
                bf16x8 a0l = ldfrag(&su[(l31)      * 136 + 64 + kk * 16 + kh * 8]);
                bf16x8 a1l = ldfrag(&su[(32 + l31) * 136 + 64 + kk * 16 + kh * 8]);
                acc[0][0] = __builtin_amdgcn_mfma_f32_32x32x16_bf16(a0h, bfh[0][kk], acc[0][0], 0, 0, 0);
                acc[0][1] = __builtin_amdgcn_mfma_f32_32x32x16_bf16(a0h, bfh[1][kk], acc[0][1], 0, 0, 0);
                acc[1][0] = __builtin_amdgcn_mfma_f32_32x32x16_bf16(a1h, bfh[0][kk], acc[1][0], 0, 0, 0);
                acc[1][1] = __builtin_amdgcn_mfma_f32_32x32x16_bf16(a1h, bfh[1][kk], acc[1][1], 0, 0, 0);
                acc[0][0] = __builtin_amdgcn_mfma_f32_32x32x16_bf16(a0l, bfh[0][kk], acc[0][0], 0, 0, 0);
                acc[0][1] = __builtin_amdgcn_mfma_f32_32x32x16_bf16(a0l, bfh[1][kk], acc[0][1], 0, 0, 0);
                acc[1][0] = __builtin_amdgcn_mfma_f32_32x32x16_bf16(a1l, bfh[0][kk], acc[1][0], 0, 0, 0);
                acc[1][1] = __builtin_amdgcn_mfma_f32_32x32x16_bf16(a1l, bfh[1][kk], acc[1][1], 0, 0, 0);
                acc[0][0] = __builtin_amdgcn_mfma_f32_32x32x16_bf16(a0h, bfl[0][kk], acc[0][0], 0, 0, 0);
                acc[0][1] = __builtin_amdgcn_mfma_f32_32x32x16_bf16(a0h, bfl[1][kk], acc[0][1], 0, 0, 0);
                acc[1][0] = __builtin_amdgcn_mfma_f32_32x32x16_bf16(a1h, bfl[0][kk], acc[1][0], 0, 0, 0);
                acc[1][1] = __builtin_amdgcn_mfma_f32_32x32x16_bf16(a1h, bfl[1][kk], acc[1][1], 0, 0, 0);
            }
#pragma unroll
            for (int mt = 0; mt < 2; ++mt)
#pragma unroll
                for (int r = 0; r < 16; ++r) {
                    float t0 = fmaf(lr, zr[r], acc[mt][0][r]); t0 = fmaf(-li, zi[r], t0);
                    float t1 = fmaf(li, zr[r], acc[mt][1][r]); t1 = fmaf(lr, zi[r], t1);
                    zr[r] = t0; zi[r] = t1;
                }
        } else if (sub < 3) {
            STAGE136(sU[(sub + 1) & 1], srow, sus);
            if (sub < 2) {
                const float4* sp = (const float4*)(ubase + (size_t)(c * LCH + (sub + 2) * 2 + stoff) * (NBB * NUU));
                f0 = sp[0]; f1 = sp[1]; f2 = sp[2]; f3 = sp[3];
            }
        }
        __syncthreads();
    }

    if (comp) {
#pragma unroll
        for (int r = 0; r < 16; ++r)
            E[(size_t)c * 4096 + crow(r, lane) * HH + ch] = make_float2(zr[r], zi[r]);
    }
}

// ---------------------------------------------------------------------------
// Carry hierarchy. cseg unchanged; cexp2 recomputes its own super-prefix
// (bit-identical to the old csup) -- one fewer launch.
// ---------------------------------------------------------------------------
__global__ __launch_bounds__(256) void k_cseg(
    const float* __restrict__ lre, const float* __restrict__ lim,
    const float2* __restrict__ E, float2* __restrict__ Esup)
{
    int g = blockIdx.x * 256 + threadIdx.x;
    int chain = g & 4095, seg = g >> 12, ch = chain & 127;
    float lrf, lif; lam_f32(lre[ch], lim[ch], lrf, lif);
    double pr = (double)lrf, pi = (double)lif;
#pragma unroll
    for (int s = 0; s < 3; ++s) { double nr = pr*pr - pi*pi, ni = 2.0*pr*pi; pr = nr; pi = ni; } // lambda^8
    double sr = 0.0, si = 0.0;
#pragma unroll 8
    for (int j = 0; j < CPS; ++j) {
        float2 e = E[((size_t)seg * CPS + j) * 4096 + chain];
        double nr = pr * sr - pi * si + (double)e.x;
        double ni = pi * sr + pr * si + (double)e.y;
        sr = nr; si = ni;
    }
    Esup[(size_t)seg * 4096 + chain] = make_float2((float)sr, (float)si);
}

__global__ __launch_bounds__(256) void k_cexp2(
    const float* __restrict__ lre, const float* __restrict__ lim,
    const float2* __restrict__ x0p, const float2* __restrict__ Esup,
    const float2* __restrict__ E, float2* __restrict__ Carry)
{
    int g = blockIdx.x * 256 + threadIdx.x;
    int chain = g & 4095, seg = g >> 12, ch = chain & 127;
    float lrf, lif; lam_f32(lre[ch], lim[ch], lrf, lif);
    double p8r = (double)lrf, p8i = (double)lif;
#pragma unroll
    for (int s = 0; s < 3; ++s) { double nr = p8r*p8r - p8i*p8i, ni = 2.0*p8r*p8i; p8r = nr; p8i = ni; } // lambda^8
    double pr = p8r, pi = p8i;
#pragma unroll
    for (int s = 0; s < 5; ++s) { double nr = pr*pr - pi*pi, ni = 2.0*pr*pi; pr = nr; pi = ni; } // lambda^256
    // super-prefix (identical op order to old k_csup)
    float2 c0 = x0p[chain];
    double cr = (double)c0.x, ci = (double)c0.y;
    for (int s = 0; s < seg; ++s) {
        float2 e = Esup[(size_t)s * 4096 + chain];
        double nr = pr * cr - pi * ci + (double)e.x;
        double ni = pi * cr + pr * ci + (double)e.y;
        cr = nr; ci = ni;
    }
    // expand within this segment
#pragma unroll 8
    for (int j = 0; j < CPS; ++j) {
        size_t idx = ((size_t)seg * CPS + j) * 4096 + chain;
        Carry[idx] = make_float2((float)cr, (float)ci);
        float2 e = E[idx];
        double nr = p8r * cr - p8i * ci + (double)e.x;
        double ni = p8i * cr + p8r * ci + (double)e.y;
        cr = nr; ci = ni;
    }
}

// ---------------------------------------------------------------------------
// Pass 2 (v5): 512 threads, role-split. Waves 0-3 scan: phase A stage sU
// (CVT), phase B Bu MFMA + scan + dump sX. Waves 4-7 out-GEMM: phase A
// consume sX(sub-1) (48 MFMA, W frags from global L1/L2), phase B store Y.
// Single sX buffer; LDS = 17408 + 66560 = 83968 B (proven launchable).
// All barriers uniform. Per-wave regs ~210 -> 2 waves/SIMD.
// ---------------------------------------------------------------------------
__global__ __launch_bounds__(512) void k_pass2(
    const float* __restrict__ U,
    const unsigned short* __restrict__ Bph, const unsigned short* __restrict__ Bpl,
    const unsigned short* __restrict__ Wph, const unsigned short* __restrict__ Wpl,
    const float* __restrict__ lre, const float* __restrict__ lim,
    const float* __restrict__ bx2y,
    const float2* __restrict__ Carry, float* __restrict__ Y)
{
    __shared__ __align__(16) unsigned short sU[64 * 136];   // 17408 B
    __shared__ __align__(16) unsigned short sX[64 * 520];   // 66560 B

    const int tid = threadIdx.x, w = tid >> 6, lane = tid & 63;
    const int l31 = lane & 31, kh = lane >> 5;
    const int c = blockIdx.x;
    const bool scanw = (w < 4);
    const int ch = (w & 3) * 32 + l31;          // scan channel
    const int g4 = w - 4;
    const int mtile = g4 & 1, ntile = (g4 >> 1) & 1;  // out-GEMM role

    float lr = 0.f, li = 0.f, ybias = 0.f;
    bf16x8 bfh[2][4], bfl[2][4];
    float zr[16], zi[16];

    // staging mapping (scan waves, tid < 256)
    const int srow = (tid & 255) >> 2, sus = (tid & 3) * 16;
    const int sb = srow & 31, stoff = srow >> 5;
    const float* ubase = U + (size_t)sb * NUU + sus;
    float4 f0, f1, f2, f3;

    // out-GEMM W bases (gemm waves)
    const unsigned short* wbh = Wph + (size_t)(ntile * 32 + l31) * NHH + kh * 8;
    const unsigned short* wbl = Wpl + (size_t)(ntile * 32 + l31) * NHH + kh * 8;

    if (scanw) {
        lam_f32(lre[ch], lim[ch], lr, li);
#pragma unroll
        for (int nt = 0; nt < 2; ++nt)
#pragma unroll
            for (int kk = 0; kk < 4; ++kk) {
                bfh[nt][kk] = ldfrag(&Bph[(size_t)(nt * HH + ch) * NUU + kk * 16 + kh * 8]);
                bfl[nt][kk] = ldfrag(&Bpl[(size_t)(nt * HH + ch) * NUU + kk * 16 + kh * 8]);
            }
#pragma unroll
        for (int r = 0; r < 16; ++r) {
            float2 v = Carry[(size_t)c * 4096 + crow(r, lane) * HH + ch];
            zr[r] = v.x; zi[r] = v.y;
        }
        const float4* sp = (const float4*)(ubase + (size_t)(c * LCH + stoff) * (NBB * NUU));
        f0 = sp[0]; f1 = sp[1]; f2 = sp[2]; f3 = sp[3];
    } else {
        ybias = bx2y[ntile * 32 + l31];
    }

    f32x16 ya0, ya1;   // gemm accumulators, live A->B

    for (int sub = 0; sub < 4; ++sub) {
        // ---- phase A ----
        if (scanw) {
            STAGE136(sU, srow, sus);
            if (sub < 3) {
                const float4* sp = (const float4*)(ubase + (size_t)(c * LCH + (sub + 1) * 2 + stoff) * (NBB * NUU));
                f0 = sp[0]; f1 = sp[1]; f2 = sp[2]; f3 = sp[3];
            }
        } else if (sub > 0) {
#pragma unroll
            for (int r = 0; r < 16; ++r) { ya0[r] = 0.f; ya1[r] = 0.f; }
#pragma unroll
            for (int kk = 0; kk < 16; ++kk) {
                bf16x8 xah = ldfrag(&sX[(mtile * 32 + l31) * 520 + kk * 16 + kh * 8]);
                bf16x8 xal = ldfrag(&sX[(mtile * 32 + l31) * 520 + 256 + kk * 16 + kh * 8]);
                bf16x8 wfh = ldfrag(wbh + kk * 16);
                bf16x8 wfl = ldfrag(wbl + kk * 16);
                ya0 = __builtin_amdgcn_mfma_f32_32x32x16_bf16(xah, wfh, ya0, 0, 0, 0);
                ya1 = __builtin_amdgcn_mfma_f32_32x32x16_bf16(xal, wfh, ya1, 0, 0, 0);
                ya1 = __builtin_amdgcn_mfma_f32_32x32x16_bf16(xah, wfl, ya1, 0, 0, 0);
            }
        }
        __syncthreads();

        // ---- phase B ----
        if (scanw) {
            f32x16 acc[2][2];
#pragma unroll
            for (int mt = 0; mt < 2; ++mt)
#pragma unroll
                for (int nt = 0; nt < 2; ++nt)
#pragma unroll
                    for (int r = 0; r < 16; ++r) acc[mt][nt][r] = 0.f;
#pragma unroll
            for (int kk = 0; kk < 4; ++kk) {
                bf16x8 a0h = ldfrag(&sU[(l31)      * 136 + kk * 16 + kh * 8]);
                bf16x8 a1h = ldfrag(&sU[(32 + l31) * 136 + kk * 16 + kh * 8]);
                bf16x8 a0l = ldfrag(&sU[(l31)      * 136 + 64 + kk * 16 + kh * 8]);
                bf16x8 a1l = ldfrag(&sU[(32 + l31) * 136 + 64 + kk * 16 + kh * 8]);
                acc[0][0] = __builtin_amdgcn_mfma_f32_32x32x16_bf16(a0h, bfh[0][kk], acc[0][0], 0, 0, 0);
                acc[0][1] = __builtin_amdgcn_mfma_f32_32x32x16_bf16(a0h, bfh[1][kk], acc[0][1], 0, 0, 0);
                acc[1][0] = __builtin_amdgcn_mfma_f32_32x32x16_bf16(a1h, bfh[0][kk], acc[1][0], 0, 0, 0);
                acc[1][1] = __builtin_amdgcn_mfma_f32_32x32x16_bf16(a1h, bfh[1][kk], acc[1][1], 0, 0, 0);
                acc[0][0] = __builtin_amdgcn_mfma_f32_32x32x16_bf16(a0l, bfh[0][kk], acc[0][0], 0, 0, 0);
                acc[0][1] = __builtin_amdgcn_mfma_f32_32x32x16_bf16(a0l, bfh[1][kk], acc[0][1], 0, 0, 0);
                acc[1][0] = __builtin_amdgcn_mfma_f32_32x32x16_bf16(a1l, bfh[0][kk], acc[1][0], 0, 0, 0);
                acc[1][1] = __builtin_amdgcn_mfma_f32_32x32x16_bf16(a1l, bfh[1][kk], acc[1][1], 0, 0, 0);
                acc[0][0] = __builtin_amdgcn_mfma_f32_32x32x16_bf16(a0h, bfl[0][kk], acc[0][0], 0, 0, 0);
                acc[0][1] = __builtin_amdgcn_mfma_f32_32x32x16_bf16(a0h, bfl[1][kk], acc[0][1], 0, 0, 0);
                acc[1][0] = __builtin_amdgcn_mfma_f32_32x32x16_bf16(a1h, bfl[0][kk], acc[1][0], 0, 0, 0);
                acc[1][1] = __builtin_amdgcn_mfma_f32_32x32x16_bf16(a1h, bfl[1][kk], acc[1][1], 0, 0, 0);
            }
#pragma unroll
            for (int mt = 0; mt < 2; ++mt)
#pragma unroll
                for (int r = 0; r < 16; ++r) {
                    float t0 = fmaf(lr, zr[r], acc[mt][0][r]); t0 = fmaf(-li, zi[r], t0);
                    float t1 = fmaf(li, zr[r], acc[mt][1][r]); t1 = fmaf(lr, zi[r], t1);
                    zr[r] = t0; zi[r] = t1;
                    bf16x2 hv, lv;
                    { __bf16 _h = (__bf16)t0; hv[0] = _h; lv[0] = (__bf16)(t0 - (float)_h); }
                    { __bf16 _h = (__bf16)t1; hv[1] = _h; lv[1] = (__bf16)(t1 - (float)_h); }
                    int rowb = (mt * 32 + crow(r, lane)) * 520;
                    *(bf16x2*)&sX[rowb + w * 64 + 2 * l31]       = hv;
                    *(bf16x2*)&sX[rowb + 256 + w * 64 + 2 * l31] = lv;
                }
        } else if (sub > 0) {
            int t = c * LCH + (sub - 1) * 2 + mtile;
#pragma unroll
            for (int r = 0; r < 16; ++r)
                Y[((size_t)t * NBB + crow(r, lane)) * NYY + ntile * 32 + l31] =
                    (ya0[r] + ya1[r]) + ybias;
        }
        __syncthreads();
    }

    // drain: out-GEMM for sub=3 (sX final contents; after last barrier)
    if (!scanw) {
#pragma unroll
        for (int r = 0; r < 16; ++r) { ya0[r] = 0.f; ya1[r] = 0.f; }
#pragma unroll
        for (int kk = 0; kk < 16; ++kk) {
            bf16x8 xah = ldfrag(&sX[(mtile * 32 + l31) * 520 + kk * 16 + kh * 8]);
            bf16x8 xal = ldfrag(&sX[(mtile * 32 + l31) * 520 + 256 + kk * 16 + kh * 8]);
            bf16x8 wfh = ldfrag(wbh + kk * 16);
            bf16x8 wfl = ldfrag(wbl + kk * 16);
            ya0 = __builtin_amdgcn_mfma_f32_32x32x16_bf16(xah, wfh, ya0, 0, 0, 0);
            ya1 = __builtin_amdgcn_mfma_f32_32x32x16_bf16(xal, wfh, ya1, 0, 0, 0);
            ya1 = __builtin_amdgcn_mfma_f32_32x32x16_bf16(xah, wfl, ya1, 0, 0, 0);
        }
        int t = c * LCH + 3 * 2 + mtile;
#pragma unroll
        for (int r = 0; r < 16; ++r)
            Y[((size_t)t * NBB + crow(r, lane)) * NYY + ntile * 32 + l31] =
                (ya0[r] + ya1[r]) + ybias;
    }
}

// ---------------------------------------------------------------------------
extern "C" void kernel_launch(void* const* d_in, const int* in_sizes, int n_in,
                              void* d_out, int out_size, void* d_ws, size_t ws_size,
                              hipStream_t stream) {
    const float* y0    = (const float*)d_in[0];
    const float* U     = (const float*)d_in[1];
    const float* lre   = (const float*)d_in[2];
    const float* lim   = (const float*)d_in[3];
    const float* B     = (const float*)d_in[4];
    const float* W_y2x = (const float*)d_in[5];
    const float* b_y2x = (const float*)d_in[6];
    const float* W_x2y = (const float*)d_in[7];
    const float* b_x2y = (const float*)d_in[8];
    float* Y = (float*)d_out;

    char* p = (char*)d_ws;
    float2* E        = (float2*)p; p += (size_t)CCH * 4096 * sizeof(float2);   // 16.8 MB
    float2* Carry    = (float2*)p; p += (size_t)CCH * 4096 * sizeof(float2);   // 16.8 MB
    float2* Esup     = (float2*)p; p += (size_t)SEGN * 4096 * sizeof(float2);  // 512 KB
    float2* x0p      = (float2*)p; p += (size_t)4096 * sizeof(float2);         // 32 KB
    unsigned short* Bph = (unsigned short*)p; p += 16384 * sizeof(unsigned short);
    unsigned short* Bpl = (unsigned short*)p; p += 16384 * sizeof(unsigned short);
    unsigned short* Wph = (unsigned short*)p; p += 16384 * sizeof(unsigned short);
    unsigned short* Wpl = (unsigned short*)p; p += 16384 * sizeof(unsigned short);

    k_prep <<<dim3(96),  dim3(256), 0, stream>>>(B, W_x2y, y0, W_y2x, b_y2x, Bph, Bpl, Wph, Wpl, x0p);
    k_pass1<<<dim3(CCH), dim3(512), 0, stream>>>(U, Bph, Bpl, lre, lim, E);
    k_cseg <<<dim3(256), dim3(256), 0, stream>>>(lre, lim, E, Esup);
    k_cexp2<<<dim3(256), dim3(256), 0, stream>>>(lre, lim, x0p, Esup, E, Carry);
    k_pass2<<<dim3(CCH), dim3(512), 0, stream>>>(U, Bph, Bpl, Wph, Wpl, lre, lim, b_x2y, Carry, Y);
}

// Round 6
// 191.805 us; speedup vs baseline: 1.5351x; 1.0245x over previous
//
#include <hip/hip_runtime.h>
#include <math.h>

// Problem constants
#define TT   4096
#define NBB  32
#define NUU  64
#define NHH  256
#define HH   128
#define NYY  64
// Chunking: 512 chunks of 8 steps; carry hierarchy: 16 supers x 32 chunks
#define LCH  8
#define CCH  512
#define SEGN 16
#define CPS  32

#define PI_HALF 1.5707963267948966f

typedef float  f32x16 __attribute__((ext_vector_type(16)));
typedef __bf16 bf16x8 __attribute__((ext_vector_type(8)));
typedef __bf16 bf16x2 __attribute__((ext_vector_type(2)));
typedef unsigned int uint4v __attribute__((ext_vector_type(4)));

// MFMA 32x32 C/D layout: row = (r&3) + 8*(r>>2) + 4*(lane>>5), col = lane&31
__device__ inline int crow(int r, int lane) { return (r & 3) + 8 * (r >> 2) + 4 * (lane >> 5); }
__device__ inline bf16x8 ldfrag(const unsigned short* p) {
    return __builtin_bit_cast(bf16x8, *(const uint4v*)p);
}

// split a float into bf16 hi + bf16 lo (hi+lo ~ exact to 2^-17 rel)
#define CVT(v, H, L) { __bf16 _h = (__bf16)(v); H = _h; L = (__bf16)((v) - (float)_h); }

// lambda in fp32 with correctly-rounded transcendentals (double -> fp32)
__device__ inline void lam_f32(float xre, float xim, float& lr, float& li) {
    float th = PI_HALF * xim;
    float rf = (float)exp(-(double)fabsf(xre));
    float cf = (float)cos((double)th);
    float sf = (float)sin((double)th);
    lr = rf * cf; li = rf * sf;
}

// stage 16 fp32 (f0..f3) as split-bf16 into a 64x136-short padded tile row
#define STAGE136(DST, SROW, SUS) { \
    bf16x8 h0, h1, l0, l1; \
    CVT(f0.x, h0[0], l0[0]); CVT(f0.y, h0[1], l0[1]); CVT(f0.z, h0[2], l0[2]); CVT(f0.w, h0[3], l0[3]); \
    CVT(f1.x, h0[4], l0[4]); CVT(f1.y, h0[5], l0[5]); CVT(f1.z, h0[6], l0[6]); CVT(f1.w, h0[7], l0[7]); \
    CVT(f2.x, h1[0], l1[0]); CVT(f2.y, h1[1], l1[1]); CVT(f2.z, h1[2], l1[2]); CVT(f2.w, h1[3], l1[3]); \
    CVT(f3.x, h1[4], l1[4]); CVT(f3.y, h1[5], l1[5]); CVT(f3.z, h1[6], l1[6]); CVT(f3.w, h1[7], l1[7]); \
    *(bf16x8*)&DST[(SROW) * 136 + (SUS)]          = h0; \
    *(bf16x8*)&DST[(SROW) * 136 + (SUS) + 8]      = h1; \
    *(bf16x8*)&DST[(SROW) * 136 + 64 + (SUS)]     = l0; \
    *(bf16x8*)&DST[(SROW) * 136 + 64 + (SUS) + 8] = l1; }

// --- swizzled LDS index helpers for pass2 (offsets in shorts) -------------
// pass2 sU (64 rows x 128): 16B chunk ^= row&15
__device__ inline int swzU(int row, int so) {
    return row * 128 + ((((so >> 3) ^ row) & 15) << 3) + (so & 7);
}
// pass2 sX (64 rows x 512): low-5 of chunk ^= row, bit5 kept
__device__ inline int swzX(int row, int so) {
    int chv = so >> 3;
    chv = (chv & 32) | ((chv ^ row) & 31);
    return row * 512 + (chv << 3) + (so & 7);
}

// ---------------------------------------------------------------------------
// Prep: x0 pairs; bf16 hi/lo split of B (plain) and W_x2y with interleaved K
// permute: Wp[y][2j] = W[y][j], Wp[y][2j+1] = W[y][j+128].
// ---------------------------------------------------------------------------
__global__ __launch_bounds__(256) void k_prep(
    const float* __restrict__ B, const float* __restrict__ W,
    const float* __restrict__ y0, const float* __restrict__ Wy2x,
    const float* __restrict__ by2x,
    unsigned short* __restrict__ Bph, unsigned short* __restrict__ Bpl,
    unsigned short* __restrict__ Wph, unsigned short* __restrict__ Wpl,
    float2* __restrict__ x0p)
{
    int bx = blockIdx.x, tid = threadIdx.x;
    if (bx < 32) {
        if (tid < HH) {
            int b = bx, ch = tid;
            float xr = by2x[ch], xi = by2x[ch + HH];
            for (int y = 0; y < NYY; ++y) {
                float v = y0[b * NYY + y];
                xr += v * Wy2x[ch * NYY + y];
                xi += v * Wy2x[(ch + HH) * NYY + y];
            }
            x0p[b * HH + ch] = make_float2(xr, xi);
        }
    } else {
        int i = (bx - 32) * 256 + tid;            // 0..16383
        float bv = B[i];
        __bf16 bh = (__bf16)bv;
        Bph[i] = __builtin_bit_cast(unsigned short, bh);
        Bpl[i] = __builtin_bit_cast(unsigned short, (__bf16)(bv - (float)bh));
        int y = i >> 8, kidx = i & 255;
        float wv = W[y * NHH + (kidx & 1) * HH + (kidx >> 1)];
        __bf16 wh = (__bf16)wv;
        Wph[i] = __builtin_bit_cast(unsigned short, wh);
        Wpl[i] = __builtin_bit_cast(unsigned short, (__bf16)(wv - (float)wh));
    }
}

// ---------------------------------------------------------------------------
// Pass 1 (v6): R2 structure (dbuf sU, reg prefetch) with B-lo moved to LDS
// so arch-reg demand ~120 <= 128 -> (256,2) gives 2 blocks/CU WITHOUT spill.
// LDS = 34816 (sU dbuf) + 36864 (sBl, 256x72-short padded) = 71680 B.
// ---------------------------------------------------------------------------
__global__ __launch_bounds__(256, 2) void k_pass1(
    const float* __restrict__ U,
    const unsigned short* __restrict__ Bph, const unsigned short* __restrict__ Bpl,
    const float* __restrict__ lre, const float* __restrict__ lim,
    float2* __restrict__ E)
{
    __shared__ __align__(16) unsigned short sU[2][64 * 136];   // 2 x 17408 B
    __shared__ __align__(16) unsigned short sBl[256 * 72];     // 36864 B

    const int tid = threadIdx.x, w = tid >> 6, lane = tid & 63;
    const int l31 = lane & 31, kh = lane >> 5;
    const int c = blockIdx.x;
    const int ch = w * 32 + l31;

    // cooperative stage of B-lo table into LDS (stride 72 shorts = 144 B,
    // 16B-aligned rows, bank-quads tile all 32 banks per 8 rows)
#pragma unroll
    for (int i = 0; i < 8; ++i) {
        int g = i * 2048 + tid * 8;
        int row = g >> 6, col = g & 63;
        *(bf16x8*)&sBl[row * 72 + col] = ldfrag(&Bpl[g]);
    }

    float lr, li; lam_f32(lre[ch], lim[ch], lr, li);

    // hoist only the HI B fragments (32 arch regs)
    bf16x8 bfh[2][4];
#pragma unroll
    for (int nt = 0; nt < 2; ++nt)
#pragma unroll
        for (int kk = 0; kk < 4; ++kk)
            bfh[nt][kk] = ldfrag(&Bph[(size_t)(nt * HH + ch) * NUU + kk * 16 + kh * 8]);

    float zr[16], zi[16];
#pragma unroll
    for (int r = 0; r < 16; ++r) { zr[r] = 0.f; zi[r] = 0.f; }

    const int srow = tid >> 2, sus = (tid & 3) * 16;
    const int sb = srow & 31, stoff = srow >> 5;
    const float* ubase = U + (size_t)sb * NUU + sus;

    float4 f0, f1, f2, f3;
    {
        const float4* sp = (const float4*)(ubase + (size_t)(c * LCH + stoff) * (NBB * NUU));
        f0 = sp[0]; f1 = sp[1]; f2 = sp[2]; f3 = sp[3];
    }

    for (int sub = 0; sub < 4; ++sub) {
        unsigned short* su = &sU[sub & 1][0];
        STAGE136(su, srow, sus);
        __syncthreads();

        if (sub < 3) {   // prefetch next sub while MFMA runs
            const float4* sp = (const float4*)(ubase + (size_t)(c * LCH + (sub + 1) * 2 + stoff) * (NBB * NUU));
            f0 = sp[0]; f1 = sp[1]; f2 = sp[2]; f3 = sp[3];
        }

        f32x16 acc[2][2];
#pragma unroll
        for (int mt = 0; mt < 2; ++mt)
#pragma unroll
            for (int nt = 0; nt < 2; ++nt)
#pragma unroll
                for (int r = 0; r < 16; ++r) acc[mt][nt][r] = 0.f;

#pragma unroll
        for (int kk = 0; kk < 4; ++kk) {
            bf16x8 a0h = ldfrag(&su[(l31)      * 136 + kk * 16 + kh * 8]);
            bf16x8 a1h = ldfrag(&su[(32 + l31) * 136 + kk * 16 + kh * 8]);
            bf16x8 a0l = ldfrag(&su[(l31)      * 136 + 64 + kk * 16 + kh * 8]);
            bf16x8 a1l = ldfrag(&su[(32 + l31) * 136 + 64 + kk * 16 + kh * 8]);
            bf16x8 bl0 = ldfrag(&sBl[(ch)      * 72 + kk * 16 + kh * 8]);
            bf16x8 bl1 = ldfrag(&sBl[(HH + ch) * 72 + kk * 16 + kh * 8]);
            acc[0][0] = __builtin_amdgcn_mfma_f32_32x32x16_bf16(a0h, bfh[0][kk], acc[0][0], 0, 0, 0);
            acc[0][1] = __builtin_amdgcn_mfma_f32_32x32x16_bf16(a0h, bfh[1][kk], acc[0][1], 0, 0, 0);
            acc[1][0] = __builtin_amdgcn_mfma_f32_32x32x16_bf16(a1h, bfh[0][kk], acc[1][0], 0, 0, 0);
            acc[1][1] = __builtin_amdgcn_mfma_f32_32x32x16_bf16(a1h, bfh[1][kk], acc[1][1], 0, 0, 0);
            acc[0][0] = __builtin_amdgcn_mfma_f32_32x32x16_bf16(a0l, bfh[0][kk], acc[0][0], 0, 0, 0);
            acc[0][1] = __builtin_amdgcn_mfma_f32_32x32x16_bf16(a0l, bfh[1][kk], acc[0][1], 0, 0, 0);
            acc[1][0] = __builtin_amdgcn_mfma_f32_32x32x16_bf16(a1l, bfh[0][kk], acc[1][0], 0, 0, 0);
            acc[1][1] = __builtin_amdgcn_mfma_f32_32x32x16_bf16(a1l, bfh[1][kk], acc[1][1], 0, 0, 0);
            acc[0][0] = __builtin_amdgcn_mfma_f32_32x32x16_bf16(a0h, bl0, acc[0][0], 0, 0, 0);
            acc[0][1] = __builtin_amdgcn_mfma_f32_32x32x16_bf16(a0h, bl1, acc[0][1], 0, 0, 0);
            acc[1][0] = __builtin_amdgcn_mfma_f32_32x32x16_bf16(a1h, bl0, acc[1][0], 0, 0, 0);
            acc[1][1] = __builtin_amdgcn_mfma_f32_32x32x16_bf16(a1h, bl1, acc[1][1], 0, 0, 0);
        }

#pragma unroll
        for (int mt = 0; mt < 2; ++mt)
#pragma unroll
            for (int r = 0; r < 16; ++r) {
                float t0 = fmaf(lr, zr[r], acc[mt][0][r]); t0 = fmaf(-li, zi[r], t0);
                float t1 = fmaf(li, zr[r], acc[mt][1][r]); t1 = fmaf(lr, zi[r], t1);
                zr[r] = t0; zi[r] = t1;
            }
        // no trailing barrier: next sub writes the other sU buffer
    }

#pragma unroll
    for (int r = 0; r < 16; ++r)
        E[(size_t)c * 4096 + crow(r, lane) * HH + ch] = make_float2(zr[r], zi[r]);
}

// ---------------------------------------------------------------------------
// Carry hierarchy: cseg + merged cexp2 (recomputes its super-prefix,
// bit-identical to the old csup+cexp pair).
// ---------------------------------------------------------------------------
__global__ __launch_bounds__(256) void k_cseg(
    const float* __restrict__ lre, const float* __restrict__ lim,
    const float2* __restrict__ E, float2* __restrict__ Esup)
{
    int g = blockIdx.x * 256 + threadIdx.x;
    int chain = g & 4095, seg = g >> 12, ch = chain & 127;
    float lrf, lif; lam_f32(lre[ch], lim[ch], lrf, lif);
    double pr = (double)lrf, pi = (double)lif;
#pragma unroll
    for (int s = 0; s < 3; ++s) { double nr = pr*pr - pi*pi, ni = 2.0*pr*pi; pr = nr; pi = ni; } // lambda^8
    double sr = 0.0, si = 0.0;
#pragma unroll 8
    for (int j = 0; j < CPS; ++j) {
        float2 e = E[((size_t)seg * CPS + j) * 4096 + chain];
        double nr = pr * sr - pi * si + (double)e.x;
        double ni = pi * sr + pr * si + (double)e.y;
        sr = nr; si = ni;
    }
    Esup[(size_t)seg * 4096 + chain] = make_float2((float)sr, (float)si);
}

__global__ __launch_bounds__(256) void k_cexp2(
    const float* __restrict__ lre, const float* __restrict__ lim,
    const float2* __restrict__ x0p, const float2* __restrict__ Esup,
    const float2* __restrict__ E, float2* __restrict__ Carry)
{
    int g = blockIdx.x * 256 + threadIdx.x;
    int chain = g & 4095, seg = g >> 12, ch = chain & 127;
    float lrf, lif; lam_f32(lre[ch], lim[ch], lrf, lif);
    double p8r = (double)lrf, p8i = (double)lif;
#pragma unroll
    for (int s = 0; s < 3; ++s) { double nr = p8r*p8r - p8i*p8i, ni = 2.0*p8r*p8i; p8r = nr; p8i = ni; } // lambda^8
    double pr = p8r, pi = p8i;
#pragma unroll
    for (int s = 0; s < 5; ++s) { double nr = pr*pr - pi*pi, ni = 2.0*pr*pi; pr = nr; pi = ni; } // lambda^256
    float2 c0 = x0p[chain];
    double cr = (double)c0.x, ci = (double)c0.y;
    for (int s = 0; s < seg; ++s) {
        float2 e = Esup[(size_t)s * 4096 + chain];
        double nr = pr * cr - pi * ci + (double)e.x;
        double ni = pi * cr + pr * ci + (double)e.y;
        cr = nr; ci = ni;
    }
#pragma unroll 8
    for (int j = 0; j < CPS; ++j) {
        size_t idx = ((size_t)seg * CPS + j) * 4096 + chain;
        Carry[idx] = make_float2((float)cr, (float)ci);
        float2 e = E[idx];
        double nr = p8r * cr - p8i * ci + (double)e.x;
        double ni = p8i * cr + p8r * ci + (double)e.y;
        cr = nr; ci = ni;
    }
}

// ---------------------------------------------------------------------------
// Pass 2: R2's measured-best kernel, verbatim (53.4 us proven).
// LDS = 16384 (sU swz) + 65536 (sX swz) = 81920 B; (256,1); VGPR 256.
// ---------------------------------------------------------------------------
__global__ __launch_bounds__(256, 1) void k_pass2(
    const float* __restrict__ U,
    const unsigned short* __restrict__ Bph, const unsigned short* __restrict__ Bpl,
    const unsigned short* __restrict__ Wph, const unsigned short* __restrict__ Wpl,
    const float* __restrict__ lre, const float* __restrict__ lim,
    const float* __restrict__ bx2y,
    const float2* __restrict__ Carry, float* __restrict__ Y)
{
    __shared__ __align__(16) unsigned short sU[64 * 128];   // 16384 B, swizzled
    __shared__ __align__(16) unsigned short sX[64 * 512];   // 65536 B, swizzled

    const int tid = threadIdx.x, w = tid >> 6, lane = tid & 63;
    const int l31 = lane & 31, kh = lane >> 5;
    const int c = blockIdx.x;
    const int ch = w * 32 + l31;             // scan channel
    const int mtile = w & 1, ntile = w >> 1; // out-GEMM tile mapping

    float lr, li; lam_f32(lre[ch], lim[ch], lr, li);
    float ybias = bx2y[ntile * 32 + l31];

    bf16x8 bfh[2][4], bfl[2][4];
#pragma unroll
    for (int nt = 0; nt < 2; ++nt)
#pragma unroll
        for (int kk = 0; kk < 4; ++kk) {
            bfh[nt][kk] = ldfrag(&Bph[(size_t)(nt * HH + ch) * NUU + kk * 16 + kh * 8]);
            bfl[nt][kk] = ldfrag(&Bpl[(size_t)(nt * HH + ch) * NUU + kk * 16 + kh * 8]);
        }

    bf16x8 wfh[16], wfl[16];
#pragma unroll
    for (int kk = 0; kk < 16; ++kk) {
        wfh[kk] = ldfrag(&Wph[(size_t)(ntile * 32 + l31) * NHH + kk * 16 + kh * 8]);
        wfl[kk] = ldfrag(&Wpl[(size_t)(ntile * 32 + l31) * NHH + kk * 16 + kh * 8]);
    }

    float zr[16], zi[16];
#pragma unroll
    for (int r = 0; r < 16; ++r) {
        float2 v = Carry[(size_t)c * 4096 + crow(r, lane) * HH + ch];
        zr[r] = v.x; zi[r] = v.y;
    }

    const int srow = tid >> 2, sus = (tid & 3) * 16;
    const int sb = srow & 31, stoff = srow >> 5;
    const float* ubase = U + (size_t)sb * NUU + sus;

    float4 f0, f1, f2, f3;
    {
        const float4* sp = (const float4*)(ubase + (size_t)(c * LCH + stoff) * (NBB * NUU));
        f0 = sp[0]; f1 = sp[1]; f2 = sp[2]; f3 = sp[3];
    }

    for (int sub = 0; sub < 4; ++sub) {
        {   // convert + write sU (swizzled)
            bf16x8 h0, h1, l0, l1;
            CVT(f0.x, h0[0], l0[0]); CVT(f0.y, h0[1], l0[1]); CVT(f0.z, h0[2], l0[2]); CVT(f0.w, h0[3], l0[3]);
            CVT(f1.x, h0[4], l0[4]); CVT(f1.y, h0[5], l0[5]); CVT(f1.z, h0[6], l0[6]); CVT(f1.w, h0[7], l0[7]);
            CVT(f2.x, h1[0], l1[0]); CVT(f2.y, h1[1], l1[1]); CVT(f2.z, h1[2], l1[2]); CVT(f2.w, h1[3], l1[3]);
            CVT(f3.x, h1[4], l1[4]); CVT(f3.y, h1[5], l1[5]); CVT(f3.z, h1[6], l1[6]); CVT(f3.w, h1[7], l1[7]);
            *(bf16x8*)&sU[swzU(srow, sus)]          = h0;
            *(bf16x8*)&sU[swzU(srow, sus + 8)]      = h1;
            *(bf16x8*)&sU[swzU(srow, 64 + sus)]     = l0;
            *(bf16x8*)&sU[swzU(srow, 64 + sus + 8)] = l1;
        }

        if (sub > 0) {  // out-GEMM for sub-1 (reads sX written before last barrier)
            f32x16 ya0, ya1, ya2;
#pragma unroll
            for (int r = 0; r < 16; ++r) { ya0[r] = 0.f; ya1[r] = 0.f; ya2[r] = 0.f; }
#pragma unroll
            for (int kk = 0; kk < 16; ++kk) {
                bf16x8 xah = ldfrag(&sX[swzX(mtile * 32 + l31, kk * 16 + kh * 8)]);
                bf16x8 xal = ldfrag(&sX[swzX(mtile * 32 + l31, 256 + kk * 16 + kh * 8)]);
                ya0 = __builtin_amdgcn_mfma_f32_32x32x16_bf16(xah, wfh[kk], ya0, 0, 0, 0);
                ya1 = __builtin_amdgcn_mfma_f32_32x32x16_bf16(xal, wfh[kk], ya1, 0, 0, 0);
                ya2 = __builtin_amdgcn_mfma_f32_32x32x16_bf16(xah, wfl[kk], ya2, 0, 0, 0);
            }
            int t = c * LCH + (sub - 1) * 2 + mtile;
#pragma unroll
            for (int r = 0; r < 16; ++r)
                Y[((size_t)t * NBB + crow(r, lane)) * NYY + ntile * 32 + l31] =
                    (ya0[r] + ya1[r]) + ya2[r] + ybias;
        }
        __syncthreads();

        if (sub < 3) {   // prefetch next sub; lands under the MFMA phase
            const float4* sp = (const float4*)(ubase + (size_t)(c * LCH + (sub + 1) * 2 + stoff) * (NBB * NUU));
            f0 = sp[0]; f1 = sp[1]; f2 = sp[2]; f3 = sp[3];
        }

        // Bu MFMA (split 3-term)
        f32x16 acc[2][2];
#pragma unroll
        for (int mt = 0; mt < 2; ++mt)
#pragma unroll
            for (int nt = 0; nt < 2; ++nt)
#pragma unroll
                for (int r = 0; r < 16; ++r) acc[mt][nt][r] = 0.f;

#pragma unroll
        for (int kk = 0; kk < 4; ++kk) {
            bf16x8 a0h = ldfrag(&sU[swzU(l31,      kk * 16 + kh * 8)]);
            bf16x8 a1h = ldfrag(&sU[swzU(32 + l31, kk * 16 + kh * 8)]);
            bf16x8 a0l = ldfrag(&sU[swzU(l31,      64 + kk * 16 + kh * 8)]);
            bf16x8 a1l = ldfrag(&sU[swzU(32 + l31, 64 + kk * 16 + kh * 8)]);
            acc[0][0] = __builtin_amdgcn_mfma_f32_32x32x16_bf16(a0h, bfh[0][kk], acc[0][0], 0, 0, 0);
            acc[0][1] = __builtin_amdgcn_mfma_f32_32x32x16_bf16(a0h, bfh[1][kk], acc[0][1], 0, 0, 0);
            acc[1][0] = __builtin_amdgcn_mfma_f32_32x32x16_bf16(a1h, bfh[0][kk], acc[1][0], 0, 0, 0);
            acc[1][1] = __builtin_amdgcn_mfma_f32_32x32x16_bf16(a1h, bfh[1][kk], acc[1][1], 0, 0, 0);
            acc[0][0] = __builtin_amdgcn_mfma_f32_32x32x16_bf16(a0l, bfh[0][kk], acc[0][0], 0, 0, 0);
            acc[0][1] = __builtin_amdgcn_mfma_f32_32x32x16_bf16(a0l, bfh[1][kk], acc[0][1], 0, 0, 0);
            acc[1][0] = __builtin_amdgcn_mfma_f32_32x32x16_bf16(a1l, bfh[0][kk], acc[1][0], 0, 0, 0);
            acc[1][1] = __builtin_amdgcn_mfma_f32_32x32x16_bf16(a1l, bfh[1][kk], acc[1][1], 0, 0, 0);
            acc[0][0] = __builtin_amdgcn_mfma_f32_32x32x16_bf16(a0h, bfl[0][kk], acc[0][0], 0, 0, 0);
            acc[0][1] = __builtin_amdgcn_mfma_f32_32x32x16_bf16(a0h, bfl[1][kk], acc[0][1], 0, 0, 0);
            acc[1][0] = __builtin_amdgcn_mfma_f32_32x32x16_bf16(a1h, bfl[0][kk], acc[1][0], 0, 0, 0);
            acc[1][1] = __builtin_amdgcn_mfma_f32_32x32x16_bf16(a1h, bfl[1][kk], acc[1][1], 0, 0, 0);
        }

        // Scan + split hi/lo dump (two b32 per (mt,r)), swizzled
#pragma unroll
        for (int mt = 0; mt < 2; ++mt)
#pragma unroll
            for (int r = 0; r < 16; ++r) {
                float t0 = fmaf(lr, zr[r], acc[mt][0][r]); t0 = fmaf(-li, zi[r], t0);
                float t1 = fmaf(li, zr[r], acc[mt][1][r]); t1 = fmaf(lr, zi[r], t1);
                zr[r] = t0; zi[r] = t1;
                bf16x2 hv, lv;
                { __bf16 _h = (__bf16)t0; hv[0] = _h; lv[0] = (__bf16)(t0 - (float)_h); }
                { __bf16 _h = (__bf16)t1; hv[1] = _h; lv[1] = (__bf16)(t1 - (float)_h); }
                int row = mt * 32 + crow(r, lane);
                *(bf16x2*)&sX[swzX(row, w * 64 + 2 * l31)]       = hv;
                *(bf16x2*)&sX[swzX(row, 256 + w * 64 + 2 * l31)] = lv;
            }
        __syncthreads();
    }

    // Drain: out-GEMM for sub=3
    {
        f32x16 ya0, ya1, ya2;
#pragma unroll
        for (int r = 0; r < 16; ++r) { ya0[r] = 0.f; ya1[r] = 0.f; ya2[r] = 0.f; }
#pragma unroll
        for (int kk = 0; kk < 16; ++kk) {
            bf16x8 xah = ldfrag(&sX[swzX(mtile * 32 + l31, kk * 16 + kh * 8)]);
            bf16x8 xal = ldfrag(&sX[swzX(mtile * 32 + l31, 256 + kk * 16 + kh * 8)]);
            ya0 = __builtin_amdgcn_mfma_f32_32x32x16_bf16(xah, wfh[kk], ya0, 0, 0, 0);
            ya1 = __builtin_amdgcn_mfma_f32_32x32x16_bf16(xal, wfh[kk], ya1, 0, 0, 0);
            ya2 = __builtin_amdgcn_mfma_f32_32x32x16_bf16(xah, wfl[kk], ya2, 0, 0, 0);
        }
        int t = c * LCH + 3 * 2 + mtile;
#pragma unroll
        for (int r = 0; r < 16; ++r)
            Y[((size_t)t * NBB + crow(r, lane)) * NYY + ntile * 32 + l31] =
                (ya0[r] + ya1[r]) + ya2[r] + ybias;
    }
}

// ---------------------------------------------------------------------------
extern "C" void kernel_launch(void* const* d_in, const int* in_sizes, int n_in,
                              void* d_out, int out_size, void* d_ws, size_t ws_size,
                              hipStream_t stream) {
    const float* y0    = (const float*)d_in[0];
    const float* U     = (const float*)d_in[1];
    const float* lre   = (const float*)d_in[2];
    const float* lim   = (const float*)d_in[3];
    const float* B     = (const float*)d_in[4];
    const float* W_y2x = (const float*)d_in[5];
    const float* b_y2x = (const float*)d_in[6];
    const float* W_x2y = (const float*)d_in[7];
    const float* b_x2y = (const float*)d_in[8];
    float* Y = (float*)d_out;

    char* p = (char*)d_ws;
    float2* E        = (float2*)p; p += (size_t)CCH * 4096 * sizeof(float2);   // 16.8 MB
    float2* Carry    = (float2*)p; p += (size_t)CCH * 4096 * sizeof(float2);   // 16.8 MB
    float2* Esup     = (float2*)p; p += (size_t)SEGN * 4096 * sizeof(float2);  // 512 KB
    float2* x0p      = (float2*)p; p += (size_t)4096 * sizeof(float2);         // 32 KB
    unsigned short* Bph = (unsigned short*)p; p += 16384 * sizeof(unsigned short);
    unsigned short* Bpl = (unsigned short*)p; p += 16384 * sizeof(unsigned short);
    unsigned short* Wph = (unsigned short*)p; p += 16384 * sizeof(unsigned short);
    unsigned short* Wpl = (unsigned short*)p; p += 16384 * sizeof(unsigned short);

    k_prep <<<dim3(96),  dim3(256), 0, stream>>>(B, W_x2y, y0, W_y2x, b_y2x, Bph, Bpl, Wph, Wpl, x0p);
    k_pass1<<<dim3(CCH), dim3(256), 0, stream>>>(U, Bph, Bpl, lre, lim, E);
    k_cseg <<<dim3(256), dim3(256), 0, stream>>>(lre, lim, E, Esup);
    k_cexp2<<<dim3(256), dim3(256), 0, stream>>>(lre, lim, x0p, Esup, E, Carry);
    k_pass2<<<dim3(CCH), dim3(256), 0, stream>>>(U, Bph, Bpl, Wph, Wpl, lre, lim, b_x2y, Carry, Y);
}

// Round 7
// 183.274 us; speedup vs baseline: 1.6066x; 1.0465x over previous
//
#include <hip/hip_runtime.h>
#include <math.h>

// Problem constants
#define TT   4096
#define NBB  32
#define NUU  64
#define NHH  256
#define HH   128
#define NYY  64
// Chunking: 512 chunks of 8 steps; carry hierarchy: 16 supers x 32 chunks
#define LCH  8
#define CCH  512
#define SEGN 16
#define CPS  32

#define PI_HALF 1.5707963267948966f

typedef float  f32x16 __attribute__((ext_vector_type(16)));
typedef __bf16 bf16x8 __attribute__((ext_vector_type(8)));
typedef __bf16 bf16x2 __attribute__((ext_vector_type(2)));
typedef unsigned int uint4v __attribute__((ext_vector_type(4)));

// MFMA 32x32 C/D layout: row = (r&3) + 8*(r>>2) + 4*(lane>>5), col = lane&31
__device__ inline int crow(int r, int lane) { return (r & 3) + 8 * (r >> 2) + 4 * (lane >> 5); }
__device__ inline bf16x8 ldfrag(const unsigned short* p) {
    return __builtin_bit_cast(bf16x8, *(const uint4v*)p);
}

// split a float into bf16 hi + bf16 lo (hi+lo ~ exact to 2^-17 rel)
#define CVT(v, H, L) { __bf16 _h = (__bf16)(v); H = _h; L = (__bf16)((v) - (float)_h); }

// lambda in fp32 with correctly-rounded transcendentals (double -> fp32)
__device__ inline void lam_f32(float xre, float xim, float& lr, float& li) {
    float th = PI_HALF * xim;
    float rf = (float)exp(-(double)fabsf(xre));
    float cf = (float)cos((double)th);
    float sf = (float)sin((double)th);
    lr = rf * cf; li = rf * sf;
}

// --- swizzled LDS index helpers for pass2 (offsets in shorts) -------------
// pass2 sU (64 rows x 128): 16B chunk ^= row&15
__device__ inline int swzU(int row, int so) {
    return row * 128 + ((((so >> 3) ^ row) & 15) << 3) + (so & 7);
}
// pass2 sX (64 rows x 512): low-5 of chunk ^= row, bit5 kept
__device__ inline int swzX(int row, int so) {
    int chv = so >> 3;
    chv = (chv & 32) | ((chv ^ row) & 31);
    return row * 512 + (chv << 3) + (so & 7);
}

// ---------------------------------------------------------------------------
// Prep: x0 pairs; bf16 hi/lo split of B (plain) and W_x2y with interleaved K
// permute: Wp[y][2j] = W[y][j], Wp[y][2j+1] = W[y][j+128].
// ---------------------------------------------------------------------------
__global__ __launch_bounds__(256) void k_prep(
    const float* __restrict__ B, const float* __restrict__ W,
    const float* __restrict__ y0, const float* __restrict__ Wy2x,
    const float* __restrict__ by2x,
    unsigned short* __restrict__ Bph, unsigned short* __restrict__ Bpl,
    unsigned short* __restrict__ Wph, unsigned short* __restrict__ Wpl,
    float2* __restrict__ x0p)
{
    int bx = blockIdx.x, tid = threadIdx.x;
    if (bx < 32) {
        if (tid < HH) {
            int b = bx, ch = tid;
            float xr = by2x[ch], xi = by2x[ch + HH];
            for (int y = 0; y < NYY; ++y) {
                float v = y0[b * NYY + y];
                xr += v * Wy2x[ch * NYY + y];
                xi += v * Wy2x[(ch + HH) * NYY + y];
            }
            x0p[b * HH + ch] = make_float2(xr, xi);
        }
    } else {
        int i = (bx - 32) * 256 + tid;            // 0..16383
        float bv = B[i];
        __bf16 bh = (__bf16)bv;
        Bph[i] = __builtin_bit_cast(unsigned short, bh);
        Bpl[i] = __builtin_bit_cast(unsigned short, (__bf16)(bv - (float)bh));
        int y = i >> 8, kidx = i & 255;
        float wv = W[y * NHH + (kidx & 1) * HH + (kidx >> 1)];
        __bf16 wh = (__bf16)wv;
        Wph[i] = __builtin_bit_cast(unsigned short, wh);
        Wpl[i] = __builtin_bit_cast(unsigned short, (__bf16)(wv - (float)wh));
    }
}

// ---------------------------------------------------------------------------
// Pass 1: R2's exact proven kernel. (256,1), dbuf sU, reg prefetch,
// hoisted bfh+bfl. Total regs ~235 -> HW gives 2 waves/SIMD, no spill.
// ---------------------------------------------------------------------------
__global__ __launch_bounds__(256, 1) void k_pass1(
    const float* __restrict__ U,
    const unsigned short* __restrict__ Bph, const unsigned short* __restrict__ Bpl,
    const float* __restrict__ lre, const float* __restrict__ lim,
    float2* __restrict__ E)
{
    __shared__ __align__(16) unsigned short sU[2][64 * 136];   // 2 x 17.4 KB

    const int tid = threadIdx.x, w = tid >> 6, lane = tid & 63;
    const int l31 = lane & 31, kh = lane >> 5;
    const int c = blockIdx.x;
    const int ch = w * 32 + l31;

    float lr, li; lam_f32(lre[ch], lim[ch], lr, li);

    bf16x8 bfh[2][4], bfl[2][4];
#pragma unroll
    for (int nt = 0; nt < 2; ++nt)
#pragma unroll
        for (int kk = 0; kk < 4; ++kk) {
            bfh[nt][kk] = ldfrag(&Bph[(size_t)(nt * HH + ch) * NUU + kk * 16 + kh * 8]);
            bfl[nt][kk] = ldfrag(&Bpl[(size_t)(nt * HH + ch) * NUU + kk * 16 + kh * 8]);
        }

    float zr[16], zi[16];
#pragma unroll
    for (int r = 0; r < 16; ++r) { zr[r] = 0.f; zi[r] = 0.f; }

    const int srow = tid >> 2, sus = (tid & 3) * 16;
    const int sb = srow & 31, stoff = srow >> 5;
    const float* ubase = U + (size_t)sb * NUU + sus;

    float4 f0, f1, f2, f3;
    {
        const float4* sp = (const float4*)(ubase + (size_t)(c * LCH + stoff) * (NBB * NUU));
        f0 = sp[0]; f1 = sp[1]; f2 = sp[2]; f3 = sp[3];
    }

    for (int sub = 0; sub < 4; ++sub) {
        unsigned short* su = &sU[sub & 1][0];
        {   // convert staged regs -> split-bf16, write LDS
            bf16x8 h0, h1, l0, l1;
            CVT(f0.x, h0[0], l0[0]); CVT(f0.y, h0[1], l0[1]); CVT(f0.z, h0[2], l0[2]); CVT(f0.w, h0[3], l0[3]);
            CVT(f1.x, h0[4], l0[4]); CVT(f1.y, h0[5], l0[5]); CVT(f1.z, h0[6], l0[6]); CVT(f1.w, h0[7], l0[7]);
            CVT(f2.x, h1[0], l1[0]); CVT(f2.y, h1[1], l1[1]); CVT(f2.z, h1[2], l1[2]); CVT(f2.w, h1[3], l1[3]);
            CVT(f3.x, h1[4], l1[4]); CVT(f3.y, h1[5], l1[5]); CVT(f3.z, h1[6], l1[6]); CVT(f3.w, h1[7], l1[7]);
            *(bf16x8*)&su[srow * 136 + sus]          = h0;
            *(bf16x8*)&su[srow * 136 + sus + 8]      = h1;
            *(bf16x8*)&su[srow * 136 + 64 + sus]     = l0;
            *(bf16x8*)&su[srow * 136 + 64 + sus + 8] = l1;
        }
        __syncthreads();

        if (sub < 3) {   // prefetch next sub while MFMA runs
            const float4* sp = (const float4*)(ubase + (size_t)(c * LCH + (sub + 1) * 2 + stoff) * (NBB * NUU));
            f0 = sp[0]; f1 = sp[1]; f2 = sp[2]; f3 = sp[3];
        }

        f32x16 acc[2][2];
#pragma unroll
        for (int mt = 0; mt < 2; ++mt)
#pragma unroll
            for (int nt = 0; nt < 2; ++nt)
#pragma unroll
                for (int r = 0; r < 16; ++r) acc[mt][nt][r] = 0.f;

#pragma unroll
        for (int kk = 0; kk < 4; ++kk) {
            bf16x8 a0h = ldfrag(&su[(l31)      * 136 + kk * 16 + kh * 8]);
            bf16x8 a1h = ldfrag(&su[(32 + l31) * 136 + kk * 16 + kh * 8]);
            bf16x8 a0l = ldfrag(&su[(l31)      * 136 + 64 + kk * 16 + kh * 8]);
            bf16x8 a1l = ldfrag(&su[(32 + l31) * 136 + 64 + kk * 16 + kh * 8]);
            acc[0][0] = __builtin_amdgcn_mfma_f32_32x32x16_bf16(a0h, bfh[0][kk], acc[0][0], 0, 0, 0);
            acc[0][1] = __builtin_amdgcn_mfma_f32_32x32x16_bf16(a0h, bfh[1][kk], acc[0][1], 0, 0, 0);
            acc[1][0] = __builtin_amdgcn_mfma_f32_32x32x16_bf16(a1h, bfh[0][kk], acc[1][0], 0, 0, 0);
            acc[1][1] = __builtin_amdgcn_mfma_f32_32x32x16_bf16(a1h, bfh[1][kk], acc[1][1], 0, 0, 0);
            acc[0][0] = __builtin_amdgcn_mfma_f32_32x32x16_bf16(a0l, bfh[0][kk], acc[0][0], 0, 0, 0);
            acc[0][1] = __builtin_amdgcn_mfma_f32_32x32x16_bf16(a0l, bfh[1][kk], acc[0][1], 0, 0, 0);
            acc[1][0] = __builtin_amdgcn_mfma_f32_32x32x16_bf16(a1l, bfh[0][kk], acc[1][0], 0, 0, 0);
            acc[1][1] = __builtin_amdgcn_mfma_f32_32x32x16_bf16(a1l, bfh[1][kk], acc[1][1], 0, 0, 0);
            acc[0][0] = __builtin_amdgcn_mfma_f32_32x32x16_bf16(a0h, bfl[0][kk], acc[0][0], 0, 0, 0);
            acc[0][1] = __builtin_amdgcn_mfma_f32_32x32x16_bf16(a0h, bfl[1][kk], acc[0][1], 0, 0, 0);
            acc[1][0] = __builtin_amdgcn_mfma_f32_32x32x16_bf16(a1h, bfl[0][kk], acc[1][0], 0, 0, 0);
            acc[1][1] = __builtin_amdgcn_mfma_f32_32x32x16_bf16(a1h, bfl[1][kk], acc[1][1], 0, 0, 0);
        }

#pragma unroll
        for (int mt = 0; mt < 2; ++mt)
#pragma unroll
            for (int r = 0; r < 16; ++r) {
                float t0 = fmaf(lr, zr[r], acc[mt][0][r]); t0 = fmaf(-li, zi[r], t0);
                float t1 = fmaf(li, zr[r], acc[mt][1][r]); t1 = fmaf(lr, zi[r], t1);
                zr[r] = t0; zi[r] = t1;
            }
        // no trailing barrier: next sub writes the other buffer
    }

#pragma unroll
    for (int r = 0; r < 16; ++r)
        E[(size_t)c * 4096 + crow(r, lane) * HH + ch] = make_float2(zr[r], zi[r]);
}

// ---------------------------------------------------------------------------
// Carry hierarchy. v7: load-all-then-chain (max memory-level parallelism
// before the serial f64 recurrence).
// ---------------------------------------------------------------------------
__global__ __launch_bounds__(256) void k_cseg(
    const float* __restrict__ lre, const float* __restrict__ lim,
    const float2* __restrict__ E, float2* __restrict__ Esup)
{
    int g = blockIdx.x * 256 + threadIdx.x;
    int chain = g & 4095, seg = g >> 12, ch = chain & 127;
    float lrf, lif; lam_f32(lre[ch], lim[ch], lrf, lif);
    double pr = (double)lrf, pi = (double)lif;
#pragma unroll
    for (int s = 0; s < 3; ++s) { double nr = pr*pr - pi*pi, ni = 2.0*pr*pi; pr = nr; pi = ni; } // lambda^8
    float2 e[CPS];
#pragma unroll
    for (int j = 0; j < CPS; ++j)
        e[j] = E[((size_t)seg * CPS + j) * 4096 + chain];
    double sr = 0.0, si = 0.0;
#pragma unroll
    for (int j = 0; j < CPS; ++j) {
        double nr = pr * sr - pi * si + (double)e[j].x;
        double ni = pi * sr + pr * si + (double)e[j].y;
        sr = nr; si = ni;
    }
    Esup[(size_t)seg * 4096 + chain] = make_float2((float)sr, (float)si);
}

__global__ __launch_bounds__(256) void k_cexp2(
    const float* __restrict__ lre, const float* __restrict__ lim,
    const float2* __restrict__ x0p, const float2* __restrict__ Esup,
    const float2* __restrict__ E, float2* __restrict__ Carry)
{
    int g = blockIdx.x * 256 + threadIdx.x;
    int chain = g & 4095, seg = g >> 12, ch = chain & 127;  // seg uniform per block
    float lrf, lif; lam_f32(lre[ch], lim[ch], lrf, lif);
    double p8r = (double)lrf, p8i = (double)lif;
#pragma unroll
    for (int s = 0; s < 3; ++s) { double nr = p8r*p8r - p8i*p8i, ni = 2.0*p8r*p8i; p8r = nr; p8i = ni; } // lambda^8
    double pr = p8r, pi = p8i;
#pragma unroll
    for (int s = 0; s < 5; ++s) { double nr = pr*pr - pi*pi, ni = 2.0*pr*pi; pr = nr; pi = ni; } // lambda^256
    // super-prefix: hoist loads, then chain (identical op order to old csup)
    float2 es[SEGN - 1];
#pragma unroll
    for (int s = 0; s < SEGN - 1; ++s)
        es[s] = Esup[(size_t)s * 4096 + chain];
    float2 c0 = x0p[chain];
    double cr = (double)c0.x, ci = (double)c0.y;
#pragma unroll
    for (int s = 0; s < SEGN - 1; ++s) {
        if (s < seg) {
            double nr = pr * cr - pi * ci + (double)es[s].x;
            double ni = pi * cr + pr * ci + (double)es[s].y;
            cr = nr; ci = ni;
        }
    }
    // expand within this segment: loads hoisted, serial chain + stores
    float2 e[CPS];
#pragma unroll
    for (int j = 0; j < CPS; ++j)
        e[j] = E[((size_t)seg * CPS + j) * 4096 + chain];
#pragma unroll
    for (int j = 0; j < CPS; ++j) {
        Carry[((size_t)seg * CPS + j) * 4096 + chain] = make_float2((float)cr, (float)ci);
        double nr = p8r * cr - p8i * ci + (double)e[j].x;
        double ni = p8i * cr + p8r * ci + (double)e[j].y;
        cr = nr; ci = ni;
    }
}

// ---------------------------------------------------------------------------
// Pass 2 (v7): R2 structure, but W and B-lo fragments de-hoisted (per-kk
// global loads, L1/L2-hot) and ya2 merged into ya1. Total regs ~230 <= 256
// -> HW gives 2 waves/SIMD at (256,1), no forced split, no spill.
// ---------------------------------------------------------------------------
__global__ __launch_bounds__(256, 1) void k_pass2(
    const float* __restrict__ U,
    const unsigned short* __restrict__ Bph, const unsigned short* __restrict__ Bpl,
    const unsigned short* __restrict__ Wph, const unsigned short* __restrict__ Wpl,
    const float* __restrict__ lre, const float* __restrict__ lim,
    const float* __restrict__ bx2y,
    const float2* __restrict__ Carry, float* __restrict__ Y)
{
    __shared__ __align__(16) unsigned short sU[64 * 128];   // 16384 B, swizzled
    __shared__ __align__(16) unsigned short sX[64 * 512];   // 65536 B, swizzled

    const int tid = threadIdx.x, w = tid >> 6, lane = tid & 63;
    const int l31 = lane & 31, kh = lane >> 5;
    const int c = blockIdx.x;
    const int ch = w * 32 + l31;             // scan channel
    const int mtile = w & 1, ntile = w >> 1; // out-GEMM tile mapping

    float lr, li; lam_f32(lre[ch], lim[ch], lr, li);
    float ybias = bx2y[ntile * 32 + l31];

    // hoist only B-hi fragments (32 regs); B-lo and W read per kk from L2
    bf16x8 bfh[2][4];
#pragma unroll
    for (int nt = 0; nt < 2; ++nt)
#pragma unroll
        for (int kk = 0; kk < 4; ++kk)
            bfh[nt][kk] = ldfrag(&Bph[(size_t)(nt * HH + ch) * NUU + kk * 16 + kh * 8]);

    const unsigned short* b0l = Bpl + (size_t)ch * NUU + kh * 8;
    const unsigned short* b1l = Bpl + (size_t)(HH + ch) * NUU + kh * 8;
    const unsigned short* wbh = Wph + (size_t)(ntile * 32 + l31) * NHH + kh * 8;
    const unsigned short* wbl = Wpl + (size_t)(ntile * 32 + l31) * NHH + kh * 8;

    float zr[16], zi[16];
#pragma unroll
    for (int r = 0; r < 16; ++r) {
        float2 v = Carry[(size_t)c * 4096 + crow(r, lane) * HH + ch];
        zr[r] = v.x; zi[r] = v.y;
    }

    const int srow = tid >> 2, sus = (tid & 3) * 16;
    const int sb = srow & 31, stoff = srow >> 5;
    const float* ubase = U + (size_t)sb * NUU + sus;

    float4 f0, f1, f2, f3;
    {
        const float4* sp = (const float4*)(ubase + (size_t)(c * LCH + stoff) * (NBB * NUU));
        f0 = sp[0]; f1 = sp[1]; f2 = sp[2]; f3 = sp[3];
    }

    for (int sub = 0; sub < 4; ++sub) {
        {   // convert + write sU (swizzled)
            bf16x8 h0, h1, l0, l1;
            CVT(f0.x, h0[0], l0[0]); CVT(f0.y, h0[1], l0[1]); CVT(f0.z, h0[2], l0[2]); CVT(f0.w, h0[3], l0[3]);
            CVT(f1.x, h0[4], l0[4]); CVT(f1.y, h0[5], l0[5]); CVT(f1.z, h0[6], l0[6]); CVT(f1.w, h0[7], l0[7]);
            CVT(f2.x, h1[0], l1[0]); CVT(f2.y, h1[1], l1[1]); CVT(f2.z, h1[2], l1[2]); CVT(f2.w, h1[3], l1[3]);
            CVT(f3.x, h1[4], l1[4]); CVT(f3.y, h1[5], l1[5]); CVT(f3.z, h1[6], l1[6]); CVT(f3.w, h1[7], l1[7]);
            *(bf16x8*)&sU[swzU(srow, sus)]          = h0;
            *(bf16x8*)&sU[swzU(srow, sus + 8)]      = h1;
            *(bf16x8*)&sU[swzU(srow, 64 + sus)]     = l0;
            *(bf16x8*)&sU[swzU(srow, 64 + sus + 8)] = l1;
        }

        if (sub > 0) {  // out-GEMM for sub-1 (reads sX written before last barrier)
            f32x16 ya0, ya1;
#pragma unroll
            for (int r = 0; r < 16; ++r) { ya0[r] = 0.f; ya1[r] = 0.f; }
#pragma unroll
            for (int kk = 0; kk < 16; ++kk) {
                bf16x8 xah = ldfrag(&sX[swzX(mtile * 32 + l31, kk * 16 + kh * 8)]);
                bf16x8 xal = ldfrag(&sX[swzX(mtile * 32 + l31, 256 + kk * 16 + kh * 8)]);
                bf16x8 wfh = ldfrag(wbh + kk * 16);
                bf16x8 wfl = ldfrag(wbl + kk * 16);
                ya0 = __builtin_amdgcn_mfma_f32_32x32x16_bf16(xah, wfh, ya0, 0, 0, 0);
                ya1 = __builtin_amdgcn_mfma_f32_32x32x16_bf16(xal, wfh, ya1, 0, 0, 0);
                ya1 = __builtin_amdgcn_mfma_f32_32x32x16_bf16(xah, wfl, ya1, 0, 0, 0);
            }
            int t = c * LCH + (sub - 1) * 2 + mtile;
#pragma unroll
            for (int r = 0; r < 16; ++r)
                Y[((size_t)t * NBB + crow(r, lane)) * NYY + ntile * 32 + l31] =
                    ya0[r] + ya1[r] + ybias;
        }
        __syncthreads();

        if (sub < 3) {   // prefetch next sub; lands under the MFMA phase
            const float4* sp = (const float4*)(ubase + (size_t)(c * LCH + (sub + 1) * 2 + stoff) * (NBB * NUU));
            f0 = sp[0]; f1 = sp[1]; f2 = sp[2]; f3 = sp[3];
        }

        // Bu MFMA (split 3-term); B-lo fragments from L2 per kk
        f32x16 acc[2][2];
#pragma unroll
        for (int mt = 0; mt < 2; ++mt)
#pragma unroll
            for (int nt = 0; nt < 2; ++nt)
#pragma unroll
                for (int r = 0; r < 16; ++r) acc[mt][nt][r] = 0.f;

#pragma unroll
        for (int kk = 0; kk < 4; ++kk) {
            bf16x8 a0h = ldfrag(&sU[swzU(l31,      kk * 16 + kh * 8)]);
            bf16x8 a1h = ldfrag(&sU[swzU(32 + l31, kk * 16 + kh * 8)]);
            bf16x8 a0l = ldfrag(&sU[swzU(l31,      64 + kk * 16 + kh * 8)]);
            bf16x8 a1l = ldfrag(&sU[swzU(32 + l31, 64 + kk * 16 + kh * 8)]);
            bf16x8 bl0 = ldfrag(b0l + kk * 16);
            bf16x8 bl1 = ldfrag(b1l + kk * 16);
            acc[0][0] = __builtin_amdgcn_mfma_f32_32x32x16_bf16(a0h, bfh[0][kk], acc[0][0], 0, 0, 0);
            acc[0][1] = __builtin_amdgcn_mfma_f32_32x32x16_bf16(a0h, bfh[1][kk], acc[0][1], 0, 0, 0);
            acc[1][0] = __builtin_amdgcn_mfma_f32_32x32x16_bf16(a1h, bfh[0][kk], acc[1][0], 0, 0, 0);
            acc[1][1] = __builtin_amdgcn_mfma_f32_32x32x16_bf16(a1h, bfh[1][kk], acc[1][1], 0, 0, 0);
            acc[0][0] = __builtin_amdgcn_mfma_f32_32x32x16_bf16(a0l, bfh[0][kk], acc[0][0], 0, 0, 0);
            acc[0][1] = __builtin_amdgcn_mfma_f32_32x32x16_bf16(a0l, bfh[1][kk], acc[0][1], 0, 0, 0);
            acc[1][0] = __builtin_amdgcn_mfma_f32_32x32x16_bf16(a1l, bfh[0][kk], acc[1][0], 0, 0, 0);
            acc[1][1] = __builtin_amdgcn_mfma_f32_32x32x16_bf16(a1l, bfh[1][kk], acc[1][1], 0, 0, 0);
            acc[0][0] = __builtin_amdgcn_mfma_f32_32x32x16_bf16(a0h, bl0, acc[0][0], 0, 0, 0);
            acc[0][1] = __builtin_amdgcn_mfma_f32_32x32x16_bf16(a0h, bl1, acc[0][1], 0, 0, 0);
            acc[1][0] = __builtin_amdgcn_mfma_f32_32x32x16_bf16(a1h, bl0, acc[1][0], 0, 0, 0);
            acc[1][1] = __builtin_amdgcn_mfma_f32_32x32x16_bf16(a1h, bl1, acc[1][1], 0, 0, 0);
        }

        // Scan + split hi/lo dump (two b32 per (mt,r)), swizzled
#pragma unroll
        for (int mt = 0; mt < 2; ++mt)
#pragma unroll
            for (int r = 0; r < 16; ++r) {
                float t0 = fmaf(lr, zr[r], acc[mt][0][r]); t0 = fmaf(-li, zi[r], t0);
                float t1 = fmaf(li, zr[r], acc[mt][1][r]); t1 = fmaf(lr, zi[r], t1);
                zr[r] = t0; zi[r] = t1;
                bf16x2 hv, lv;
                { __bf16 _h = (__bf16)t0; hv[0] = _h; lv[0] = (__bf16)(t0 - (float)_h); }
                { __bf16 _h = (__bf16)t1; hv[1] = _h; lv[1] = (__bf16)(t1 - (float)_h); }
                int row = mt * 32 + crow(r, lane);
                *(bf16x2*)&sX[swzX(row, w * 64 + 2 * l31)]       = hv;
                *(bf16x2*)&sX[swzX(row, 256 + w * 64 + 2 * l31)] = lv;
            }
        __syncthreads();
    }

    // Drain: out-GEMM for sub=3
    {
        f32x16 ya0, ya1;
#pragma unroll
        for (int r = 0; r < 16; ++r) { ya0[r] = 0.f; ya1[r] = 0.f; }
#pragma unroll
        for (int kk = 0; kk < 16; ++kk) {
            bf16x8 xah = ldfrag(&sX[swzX(mtile * 32 + l31, kk * 16 + kh * 8)]);
            bf16x8 xal = ldfrag(&sX[swzX(mtile * 32 + l31, 256 + kk * 16 + kh * 8)]);
            bf16x8 wfh = ldfrag(wbh + kk * 16);
            bf16x8 wfl = ldfrag(wbl + kk * 16);
            ya0 = __builtin_amdgcn_mfma_f32_32x32x16_bf16(xah, wfh, ya0, 0, 0, 0);
            ya1 = __builtin_amdgcn_mfma_f32_32x32x16_bf16(xal, wfh, ya1, 0, 0, 0);
            ya1 = __builtin_amdgcn_mfma_f32_32x32x16_bf16(xah, wfl, ya1, 0, 0, 0);
        }
        int t = c * LCH + 3 * 2 + mtile;
#pragma unroll
        for (int r = 0; r < 16; ++r)
            Y[((size_t)t * NBB + crow(r, lane)) * NYY + ntile * 32 + l31] =
                ya0[r] + ya1[r] + ybias;
    }
}

// ---------------------------------------------------------------------------
extern "C" void kernel_launch(void* const* d_in, const int* in_sizes, int n_in,
                              void* d_out, int out_size, void* d_ws, size_t ws_size,
                              hipStream_t stream) {
    const float* y0    = (const float*)d_in[0];
    const float* U     = (const float*)d_in[1];
    const float* lre   = (const float*)d_in[2];
    const float* lim   = (const float*)d_in[3];
    const float* B     = (const float*)d_in[4];
    const float* W_y2x = (const float*)d_in[5];
    const float* b_y2x = (const float*)d_in[6];
    const float* W_x2y = (const float*)d_in[7];
    const float* b_x2y = (const float*)d_in[8];
    float* Y = (float*)d_out;

    char* p = (char*)d_ws;
    float2* E        = (float2*)p; p += (size_t)CCH * 4096 * sizeof(float2);   // 16.8 MB
    float2* Carry    = (float2*)p; p += (size_t)CCH * 4096 * sizeof(float2);   // 16.8 MB
    float2* Esup     = (float2*)p; p += (size_t)SEGN * 4096 * sizeof(float2);  // 512 KB
    float2* x0p      = (float2*)p; p += (size_t)4096 * sizeof(float2);         // 32 KB
    unsigned short* Bph = (unsigned short*)p; p += 16384 * sizeof(unsigned short);
    unsigned short* Bpl = (unsigned short*)p; p += 16384 * sizeof(unsigned short);
    unsigned short* Wph = (unsigned short*)p; p += 16384 * sizeof(unsigned short);
    unsigned short* Wpl = (unsigned short*)p; p += 16384 * sizeof(unsigned short);

    k_prep <<<dim3(96),  dim3(256), 0, stream>>>(B, W_x2y, y0, W_y2x, b_y2x, Bph, Bpl, Wph, Wpl, x0p);
    k_pass1<<<dim3(CCH), dim3(256), 0, stream>>>(U, Bph, Bpl, lre, lim, E);
    k_cseg <<<dim3(256), dim3(256), 0, stream>>>(lre, lim, E, Esup);
    k_cexp2<<<dim3(256), dim3(256), 0, stream>>>(lre, lim, x0p, Esup, E, Carry);
    k_pass2<<<dim3(CCH), dim3(256), 0, stream>>>(U, Bph, Bpl, Wph, Wpl, lre, lim, b_x2y, Carry, Y);
}

// Round 9
// 170.796 us; speedup vs baseline: 1.7240x; 1.0731x over previous
//
#include <hip/hip_runtime.h>
#include <math.h>

// Problem constants
#define TT   4096
#define NBB  32
#define NUU  64
#define NHH  256
#define HH   128
#define NYY  64
// Chunking: 512 chunks of 8 steps; carry hierarchy: 16 supers x 32 chunks
#define LCH  8
#define CCH  512
#define SEGN 16
#define CPS  32

#define PI_HALF 1.5707963267948966f

typedef float  f32x16 __attribute__((ext_vector_type(16)));
typedef __bf16 bf16x8 __attribute__((ext_vector_type(8)));
typedef __bf16 bf16x2 __attribute__((ext_vector_type(2)));
typedef unsigned int uint4v __attribute__((ext_vector_type(4)));

// MFMA 32x32 C/D layout: row = (r&3) + 8*(r>>2) + 4*(lane>>5), col = lane&31
__device__ inline int crow(int r, int lane) { return (r & 3) + 8 * (r >> 2) + 4 * (lane >> 5); }
__device__ inline bf16x8 ldfrag(const unsigned short* p) {
    return __builtin_bit_cast(bf16x8, *(const uint4v*)p);
}

// split a float into bf16 hi + bf16 lo (hi+lo ~ exact to 2^-17 rel)
#define CVT(v, H, L) { __bf16 _h = (__bf16)(v); H = _h; L = (__bf16)((v) - (float)_h); }

// lambda in fp32 with correctly-rounded transcendentals (double -> fp32)
__device__ inline void lam_f32(float xre, float xim, float& lr, float& li) {
    float th = PI_HALF * xim;
    float rf = (float)exp(-(double)fabsf(xre));
    float cf = (float)cos((double)th);
    float sf = (float)sin((double)th);
    lr = rf * cf; li = rf * sf;
}

// --- swizzled LDS index helpers for pass2 (offsets in shorts) -------------
// pass2 sU (64 rows x 128): 16B chunk ^= row&15
__device__ inline int swzU(int row, int so) {
    return row * 128 + ((((so >> 3) ^ row) & 15) << 3) + (so & 7);
}
// pass2 sX (64 rows x 512): low-5 of chunk ^= row, bit5 kept
__device__ inline int swzX(int row, int so) {
    int chv = so >> 3;
    chv = (chv & 32) | ((chv ^ row) & 31);
    return row * 512 + (chv << 3) + (so & 7);
}

// ---------------------------------------------------------------------------
// Prep: x0 pairs; bf16 hi/lo split of B (plain) and W_x2y with interleaved K
// permute: Wp[y][2j] = W[y][j], Wp[y][2j+1] = W[y][j+128].
// ---------------------------------------------------------------------------
__global__ __launch_bounds__(256) void k_prep(
    const float* __restrict__ B, const float* __restrict__ W,
    const float* __restrict__ y0, const float* __restrict__ Wy2x,
    const float* __restrict__ by2x,
    unsigned short* __restrict__ Bph, unsigned short* __restrict__ Bpl,
    unsigned short* __restrict__ Wph, unsigned short* __restrict__ Wpl,
    float2* __restrict__ x0p)
{
    int bx = blockIdx.x, tid = threadIdx.x;
    if (bx < 32) {
        if (tid < HH) {
            int b = bx, ch = tid;
            float xr = by2x[ch], xi = by2x[ch + HH];
            for (int y = 0; y < NYY; ++y) {
                float v = y0[b * NYY + y];
                xr += v * Wy2x[ch * NYY + y];
                xi += v * Wy2x[(ch + HH) * NYY + y];
            }
            x0p[b * HH + ch] = make_float2(xr, xi);
        }
    } else {
        int i = (bx - 32) * 256 + tid;            // 0..16383
        float bv = B[i];
        __bf16 bh = (__bf16)bv;
        Bph[i] = __builtin_bit_cast(unsigned short, bh);
        Bpl[i] = __builtin_bit_cast(unsigned short, (__bf16)(bv - (float)bh));
        int y = i >> 8, kidx = i & 255;
        float wv = W[y * NHH + (kidx & 1) * HH + (kidx >> 1)];
        __bf16 wh = (__bf16)wv;
        Wph[i] = __builtin_bit_cast(unsigned short, wh);
        Wpl[i] = __builtin_bit_cast(unsigned short, (__bf16)(wv - (float)wh));
    }
}

// ---------------------------------------------------------------------------
// Pass 1: R2's exact proven kernel. (256,1), dbuf sU, reg prefetch,
// hoisted bfh+bfl. Synchronous staging (no async LDS DMA -> no races).
// ---------------------------------------------------------------------------
__global__ __launch_bounds__(256, 1) void k_pass1(
    const float* __restrict__ U,
    const unsigned short* __restrict__ Bph, const unsigned short* __restrict__ Bpl,
    const float* __restrict__ lre, const float* __restrict__ lim,
    float2* __restrict__ E)
{
    __shared__ __align__(16) unsigned short sU[2][64 * 136];   // 2 x 17.4 KB

    const int tid = threadIdx.x, w = tid >> 6, lane = tid & 63;
    const int l31 = lane & 31, kh = lane >> 5;
    const int c = blockIdx.x;
    const int ch = w * 32 + l31;

    float lr, li; lam_f32(lre[ch], lim[ch], lr, li);

    bf16x8 bfh[2][4], bfl[2][4];
#pragma unroll
    for (int nt = 0; nt < 2; ++nt)
#pragma unroll
        for (int kk = 0; kk < 4; ++kk) {
            bfh[nt][kk] = ldfrag(&Bph[(size_t)(nt * HH + ch) * NUU + kk * 16 + kh * 8]);
            bfl[nt][kk] = ldfrag(&Bpl[(size_t)(nt * HH + ch) * NUU + kk * 16 + kh * 8]);
        }

    float zr[16], zi[16];
#pragma unroll
    for (int r = 0; r < 16; ++r) { zr[r] = 0.f; zi[r] = 0.f; }

    const int srow = tid >> 2, sus = (tid & 3) * 16;
    const int sb = srow & 31, stoff = srow >> 5;
    const float* ubase = U + (size_t)sb * NUU + sus;

    float4 f0, f1, f2, f3;
    {
        const float4* sp = (const float4*)(ubase + (size_t)(c * LCH + stoff) * (NBB * NUU));
        f0 = sp[0]; f1 = sp[1]; f2 = sp[2]; f3 = sp[3];
    }

    for (int sub = 0; sub < 4; ++sub) {
        unsigned short* su = &sU[sub & 1][0];
        {   // convert staged regs -> split-bf16, write LDS
            bf16x8 h0, h1, l0, l1;
            CVT(f0.x, h0[0], l0[0]); CVT(f0.y, h0[1], l0[1]); CVT(f0.z, h0[2], l0[2]); CVT(f0.w, h0[3], l0[3]);
            CVT(f1.x, h0[4], l0[4]); CVT(f1.y, h0[5], l0[5]); CVT(f1.z, h0[6], l0[6]); CVT(f1.w, h0[7], l0[7]);
            CVT(f2.x, h1[0], l1[0]); CVT(f2.y, h1[1], l1[1]); CVT(f2.z, h1[2], l1[2]); CVT(f2.w, h1[3], l1[3]);
            CVT(f3.x, h1[4], l1[4]); CVT(f3.y, h1[5], l1[5]); CVT(f3.z, h1[6], l1[6]); CVT(f3.w, h1[7], l1[7]);
            *(bf16x8*)&su[srow * 136 + sus]          = h0;
            *(bf16x8*)&su[srow * 136 + sus + 8]      = h1;
            *(bf16x8*)&su[srow * 136 + 64 + sus]     = l0;
            *(bf16x8*)&su[srow * 136 + 64 + sus + 8] = l1;
        }
        __syncthreads();

        if (sub < 3) {   // prefetch next sub while MFMA runs
            const float4* sp = (const float4*)(ubase + (size_t)(c * LCH + (sub + 1) * 2 + stoff) * (NBB * NUU));
            f0 = sp[0]; f1 = sp[1]; f2 = sp[2]; f3 = sp[3];
        }

        f32x16 acc[2][2];
#pragma unroll
        for (int mt = 0; mt < 2; ++mt)
#pragma unroll
            for (int nt = 0; nt < 2; ++nt)
#pragma unroll
                for (int r = 0; r < 16; ++r) acc[mt][nt][r] = 0.f;

#pragma unroll
        for (int kk = 0; kk < 4; ++kk) {
            bf16x8 a0h = ldfrag(&su[(l31)      * 136 + kk * 16 + kh * 8]);
            bf16x8 a1h = ldfrag(&su[(32 + l31) * 136 + kk * 16 + kh * 8]);
            bf16x8 a0l = ldfrag(&su[(l31)      * 136 + 64 + kk * 16 + kh * 8]);
            bf16x8 a1l = ldfrag(&su[(32 + l31) * 136 + 64 + kk * 16 + kh * 8]);
            acc[0][0] = __builtin_amdgcn_mfma_f32_32x32x16_bf16(a0h, bfh[0][kk], acc[0][0], 0, 0, 0);
            acc[0][1] = __builtin_amdgcn_mfma_f32_32x32x16_bf16(a0h, bfh[1][kk], acc[0][1], 0, 0, 0);
            acc[1][0] = __builtin_amdgcn_mfma_f32_32x32x16_bf16(a1h, bfh[0][kk], acc[1][0], 0, 0, 0);
            acc[1][1] = __builtin_amdgcn_mfma_f32_32x32x16_bf16(a1h, bfh[1][kk], acc[1][1], 0, 0, 0);
            acc[0][0] = __builtin_amdgcn_mfma_f32_32x32x16_bf16(a0l, bfh[0][kk], acc[0][0], 0, 0, 0);
            acc[0][1] = __builtin_amdgcn_mfma_f32_32x32x16_bf16(a0l, bfh[1][kk], acc[0][1], 0, 0, 0);
            acc[1][0] = __builtin_amdgcn_mfma_f32_32x32x16_bf16(a1l, bfh[0][kk], acc[1][0], 0, 0, 0);
            acc[1][1] = __builtin_amdgcn_mfma_f32_32x32x16_bf16(a1l, bfh[1][kk], acc[1][1], 0, 0, 0);
            acc[0][0] = __builtin_amdgcn_mfma_f32_32x32x16_bf16(a0h, bfl[0][kk], acc[0][0], 0, 0, 0);
            acc[0][1] = __builtin_amdgcn_mfma_f32_32x32x16_bf16(a0h, bfl[1][kk], acc[0][1], 0, 0, 0);
            acc[1][0] = __builtin_amdgcn_mfma_f32_32x32x16_bf16(a1h, bfl[0][kk], acc[1][0], 0, 0, 0);
            acc[1][1] = __builtin_amdgcn_mfma_f32_32x32x16_bf16(a1h, bfl[1][kk], acc[1][1], 0, 0, 0);
        }

#pragma unroll
        for (int mt = 0; mt < 2; ++mt)
#pragma unroll
            for (int r = 0; r < 16; ++r) {
                float t0 = fmaf(lr, zr[r], acc[mt][0][r]); t0 = fmaf(-li, zi[r], t0);
                float t1 = fmaf(li, zr[r], acc[mt][1][r]); t1 = fmaf(lr, zi[r], t1);
                zr[r] = t0; zi[r] = t1;
            }
        // no trailing barrier: next sub writes the other buffer
    }

#pragma unroll
    for (int r = 0; r < 16; ++r)
        E[(size_t)c * 4096 + crow(r, lane) * HH + ch] = make_float2(zr[r], zi[r]);
}

// ---------------------------------------------------------------------------
// Carry hierarchy: cseg + merged cexp2 (recomputes its super-prefix,
// bit-identical to the old csup+cexp pair). Load-all-then-chain forms.
// ---------------------------------------------------------------------------
__global__ __launch_bounds__(256) void k_cseg(
    const float* __restrict__ lre, const float* __restrict__ lim,
    const float2* __restrict__ E, float2* __restrict__ Esup)
{
    int g = blockIdx.x * 256 + threadIdx.x;
    int chain = g & 4095, seg = g >> 12, ch = chain & 127;
    float lrf, lif; lam_f32(lre[ch], lim[ch], lrf, lif);
    double pr = (double)lrf, pi = (double)lif;
#pragma unroll
    for (int s = 0; s < 3; ++s) { double nr = pr*pr - pi*pi, ni = 2.0*pr*pi; pr = nr; pi = ni; } // lambda^8
    float2 e[CPS];
#pragma unroll
    for (int j = 0; j < CPS; ++j)
        e[j] = E[((size_t)seg * CPS + j) * 4096 + chain];
    double sr = 0.0, si = 0.0;
#pragma unroll
    for (int j = 0; j < CPS; ++j) {
        double nr = pr * sr - pi * si + (double)e[j].x;
        double ni = pi * sr + pr * si + (double)e[j].y;
        sr = nr; si = ni;
    }
    Esup[(size_t)seg * 4096 + chain] = make_float2((float)sr, (float)si);
}

__global__ __launch_bounds__(256) void k_cexp2(
    const float* __restrict__ lre, const float* __restrict__ lim,
    const float2* __restrict__ x0p, const float2* __restrict__ Esup,
    const float2* __restrict__ E, float2* __restrict__ Carry)
{
    int g = blockIdx.x * 256 + threadIdx.x;
    int chain = g & 4095, seg = g >> 12, ch = chain & 127;
    float lrf, lif; lam_f32(lre[ch], lim[ch], lrf, lif);
    double p8r = (double)lrf, p8i = (double)lif;
#pragma unroll
    for (int s = 0; s < 3; ++s) { double nr = p8r*p8r - p8i*p8i, ni = 2.0*p8r*p8i; p8r = nr; p8i = ni; } // lambda^8
    double pr = p8r, pi = p8i;
#pragma unroll
    for (int s = 0; s < 5; ++s) { double nr = pr*pr - pi*pi, ni = 2.0*pr*pi; pr = nr; pi = ni; } // lambda^256
    float2 es[SEGN - 1];
#pragma unroll
    for (int s = 0; s < SEGN - 1; ++s)
        es[s] = Esup[(size_t)s * 4096 + chain];
    float2 c0 = x0p[chain];
    double cr = (double)c0.x, ci = (double)c0.y;
#pragma unroll
    for (int s = 0; s < SEGN - 1; ++s) {
        if (s < seg) {
            double nr = pr * cr - pi * ci + (double)es[s].x;
            double ni = pi * cr + pr * ci + (double)es[s].y;
            cr = nr; ci = ni;
        }
    }
    float2 e[CPS];
#pragma unroll
    for (int j = 0; j < CPS; ++j)
        e[j] = E[((size_t)seg * CPS + j) * 4096 + chain];
#pragma unroll
    for (int j = 0; j < CPS; ++j) {
        Carry[((size_t)seg * CPS + j) * 4096 + chain] = make_float2((float)cr, (float)ci);
        double nr = p8r * cr - p8i * ci + (double)e[j].x;
        double ni = p8i * cr + p8r * ci + (double)e[j].y;
        cr = nr; ci = ni;
    }
}

// ---------------------------------------------------------------------------
// Pass 2: R2's measured-best kernel, verbatim (53.4 / 53.3 us in two runs).
// LDS = 16384 (sU swz) + 65536 (sX swz) = 81920 B; (256,1); VGPR 256.
// ---------------------------------------------------------------------------
__global__ __launch_bounds__(256, 1) void k_pass2(
    const float* __restrict__ U,
    const unsigned short* __restrict__ Bph, const unsigned short* __restrict__ Bpl,
    const unsigned short* __restrict__ Wph, const unsigned short* __restrict__ Wpl,
    const float* __restrict__ lre, const float* __restrict__ lim,
    const float* __restrict__ bx2y,
    const float2* __restrict__ Carry, float* __restrict__ Y)
{
    __shared__ __align__(16) unsigned short sU[64 * 128];   // 16384 B, swizzled
    __shared__ __align__(16) unsigned short sX[64 * 512];   // 65536 B, swizzled

    const int tid = threadIdx.x, w = tid >> 6, lane = tid & 63;
    const int l31 = lane & 31, kh = lane >> 5;
    const int c = blockIdx.x;
    const int ch = w * 32 + l31;             // scan channel
    const int mtile = w & 1, ntile = w >> 1; // out-GEMM tile mapping

    float lr, li; lam_f32(lre[ch], lim[ch], lr, li);
    float ybias = bx2y[ntile * 32 + l31];

    bf16x8 bfh[2][4], bfl[2][4];
#pragma unroll
    for (int nt = 0; nt < 2; ++nt)
#pragma unroll
        for (int kk = 0; kk < 4; ++kk) {
            bfh[nt][kk] = ldfrag(&Bph[(size_t)(nt * HH + ch) * NUU + kk * 16 + kh * 8]);
            bfl[nt][kk] = ldfrag(&Bpl[(size_t)(nt * HH + ch) * NUU + kk * 16 + kh * 8]);
        }

    bf16x8 wfh[16], wfl[16];
#pragma unroll
    for (int kk = 0; kk < 16; ++kk) {
        wfh[kk] = ldfrag(&Wph[(size_t)(ntile * 32 + l31) * NHH + kk * 16 + kh * 8]);
        wfl[kk] = ldfrag(&Wpl[(size_t)(ntile * 32 + l31) * NHH + kk * 16 + kh * 8]);
    }

    float zr[16], zi[16];
#pragma unroll
    for (int r = 0; r < 16; ++r) {
        float2 v = Carry[(size_t)c * 4096 + crow(r, lane) * HH + ch];
        zr[r] = v.x; zi[r] = v.y;
    }

    const int srow = tid >> 2, sus = (tid & 3) * 16;
    const int sb = srow & 31, stoff = srow >> 5;
    const float* ubase = U + (size_t)sb * NUU + sus;

    float4 f0, f1, f2, f3;
    {
        const float4* sp = (const float4*)(ubase + (size_t)(c * LCH + stoff) * (NBB * NUU));
        f0 = sp[0]; f1 = sp[1]; f2 = sp[2]; f3 = sp[3];
    }

    for (int sub = 0; sub < 4; ++sub) {
        {   // convert + write sU (swizzled)
            bf16x8 h0, h1, l0, l1;
            CVT(f0.x, h0[0], l0[0]); CVT(f0.y, h0[1], l0[1]); CVT(f0.z, h0[2], l0[2]); CVT(f0.w, h0[3], l0[3]);
            CVT(f1.x, h0[4], l0[4]); CVT(f1.y, h0[5], l0[5]); CVT(f1.z, h0[6], l0[6]); CVT(f1.w, h0[7], l0[7]);
            CVT(f2.x, h1[0], l1[0]); CVT(f2.y, h1[1], l1[1]); CVT(f2.z, h1[2], l1[2]); CVT(f2.w, h1[3], l1[3]);
            CVT(f3.x, h1[4], l1[4]); CVT(f3.y, h1[5], l1[5]); CVT(f3.z, h1[6], l1[6]); CVT(f3.w, h1[7], l1[7]);
            *(bf16x8*)&sU[swzU(srow, sus)]          = h0;
            *(bf16x8*)&sU[swzU(srow, sus + 8)]      = h1;
            *(bf16x8*)&sU[swzU(srow, 64 + sus)]     = l0;
            *(bf16x8*)&sU[swzU(srow, 64 + sus + 8)] = l1;
        }

        if (sub > 0) {  // out-GEMM for sub-1 (reads sX written before last barrier)
            f32x16 ya0, ya1, ya2;
#pragma unroll
            for (int r = 0; r < 16; ++r) { ya0[r] = 0.f; ya1[r] = 0.f; ya2[r] = 0.f; }
#pragma unroll
            for (int kk = 0; kk < 16; ++kk) {
                bf16x8 xah = ldfrag(&sX[swzX(mtile * 32 + l31, kk * 16 + kh * 8)]);
                bf16x8 xal = ldfrag(&sX[swzX(mtile * 32 + l31, 256 + kk * 16 + kh * 8)]);
                ya0 = __builtin_amdgcn_mfma_f32_32x32x16_bf16(xah, wfh[kk], ya0, 0, 0, 0);
                ya1 = __builtin_amdgcn_mfma_f32_32x32x16_bf16(xal, wfh[kk], ya1, 0, 0, 0);
                ya2 = __builtin_amdgcn_mfma_f32_32x32x16_bf16(xah, wfl[kk], ya2, 0, 0, 0);
            }
            int t = c * LCH + (sub - 1) * 2 + mtile;
#pragma unroll
            for (int r = 0; r < 16; ++r)
                Y[((size_t)t * NBB + crow(r, lane)) * NYY + ntile * 32 + l31] =
                    (ya0[r] + ya1[r]) + ya2[r] + ybias;
        }
        __syncthreads();

        if (sub < 3) {   // prefetch next sub; lands under the MFMA phase
            const float4* sp = (const float4*)(ubase + (size_t)(c * LCH + (sub + 1) * 2 + stoff) * (NBB * NUU));
            f0 = sp[0]; f1 = sp[1]; f2 = sp[2]; f3 = sp[3];
        }

        // Bu MFMA (split 3-term)
        f32x16 acc[2][2];
#pragma unroll
        for (int mt = 0; mt < 2; ++mt)
#pragma unroll
            for (int nt = 0; nt < 2; ++nt)
#pragma unroll
                for (int r = 0; r < 16; ++r) acc[mt][nt][r] = 0.f;

#pragma unroll
        for (int kk = 0; kk < 4; ++kk) {
            bf16x8 a0h = ldfrag(&sU[swzU(l31,      kk * 16 + kh * 8)]);
            bf16x8 a1h = ldfrag(&sU[swzU(32 + l31, kk * 16 + kh * 8)]);
            bf16x8 a0l = ldfrag(&sU[swzU(l31,      64 + kk * 16 + kh * 8)]);
            bf16x8 a1l = ldfrag(&sU[swzU(32 + l31, 64 + kk * 16 + kh * 8)]);
            acc[0][0] = __builtin_amdgcn_mfma_f32_32x32x16_bf16(a0h, bfh[0][kk], acc[0][0], 0, 0, 0);
            acc[0][1] = __builtin_amdgcn_mfma_f32_32x32x16_bf16(a0h, bfh[1][kk], acc[0][1], 0, 0, 0);
            acc[1][0] = __builtin_amdgcn_mfma_f32_32x32x16_bf16(a1h, bfh[0][kk], acc[1][0], 0, 0, 0);
            acc[1][1] = __builtin_amdgcn_mfma_f32_32x32x16_bf16(a1h, bfh[1][kk], acc[1][1], 0, 0, 0);
            acc[0][0] = __builtin_amdgcn_mfma_f32_32x32x16_bf16(a0l, bfh[0][kk], acc[0][0], 0, 0, 0);
            acc[0][1] = __builtin_amdgcn_mfma_f32_32x32x16_bf16(a0l, bfh[1][kk], acc[0][1], 0, 0, 0);
            acc[1][0] = __builtin_amdgcn_mfma_f32_32x32x16_bf16(a1l, bfh[0][kk], acc[1][0], 0, 0, 0);
            acc[1][1] = __builtin_amdgcn_mfma_f32_32x32x16_bf16(a1l, bfh[1][kk], acc[1][1], 0, 0, 0);
            acc[0][0] = __builtin_amdgcn_mfma_f32_32x32x16_bf16(a0h, bfl[0][kk], acc[0][0], 0, 0, 0);
            acc[0][1] = __builtin_amdgcn_mfma_f32_32x32x16_bf16(a0h, bfl[1][kk], acc[0][1], 0, 0, 0);
            acc[1][0] = __builtin_amdgcn_mfma_f32_32x32x16_bf16(a1h, bfl[0][kk], acc[1][0], 0, 0, 0);
            acc[1][1] = __builtin_amdgcn_mfma_f32_32x32x16_bf16(a1h, bfl[1][kk], acc[1][1], 0, 0, 0);
        }

        // Scan + split hi/lo dump (two b32 per (mt,r)), swizzled
#pragma unroll
        for (int mt = 0; mt < 2; ++mt)
#pragma unroll
            for (int r = 0; r < 16; ++r) {
                float t0 = fmaf(lr, zr[r], acc[mt][0][r]); t0 = fmaf(-li, zi[r], t0);
                float t1 = fmaf(li, zr[r], acc[mt][1][r]); t1 = fmaf(lr, zi[r], t1);
                zr[r] = t0; zi[r] = t1;
                bf16x2 hv, lv;
                { __bf16 _h = (__bf16)t0; hv[0] = _h; lv[0] = (__bf16)(t0 - (float)_h); }
                { __bf16 _h = (__bf16)t1; hv[1] = _h; lv[1] = (__bf16)(t1 - (float)_h); }
                int row = mt * 32 + crow(r, lane);
                *(bf16x2*)&sX[swzX(row, w * 64 + 2 * l31)]       = hv;
                *(bf16x2*)&sX[swzX(row, 256 + w * 64 + 2 * l31)] = lv;
            }
        __syncthreads();
    }

    // Drain: out-GEMM for sub=3
    {
        f32x16 ya0, ya1, ya2;
#pragma unroll
        for (int r = 0; r < 16; ++r) { ya0[r] = 0.f; ya1[r] = 0.f; ya2[r] = 0.f; }
#pragma unroll
        for (int kk = 0; kk < 16; ++kk) {
            bf16x8 xah = ldfrag(&sX[swzX(mtile * 32 + l31, kk * 16 + kh * 8)]);
            bf16x8 xal = ldfrag(&sX[swzX(mtile * 32 + l31, 256 + kk * 16 + kh * 8)]);
            ya0 = __builtin_amdgcn_mfma_f32_32x32x16_bf16(xah, wfh[kk], ya0, 0, 0, 0);
            ya1 = __builtin_amdgcn_mfma_f32_32x32x16_bf16(xal, wfh[kk], ya1, 0, 0, 0);
            ya2 = __builtin_amdgcn_mfma_f32_32x32x16_bf16(xah, wfl[kk], ya2, 0, 0, 0);
        }
        int t = c * LCH + 3 * 2 + mtile;
#pragma unroll
        for (int r = 0; r < 16; ++r)
            Y[((size_t)t * NBB + crow(r, lane)) * NYY + ntile * 32 + l31] =
                (ya0[r] + ya1[r]) + ya2[r] + ybias;
    }
}

// ---------------------------------------------------------------------------
extern "C" void kernel_launch(void* const* d_in, const int* in_sizes, int n_in,
                              void* d_out, int out_size, void* d_ws, size_t ws_size,
                              hipStream_t stream) {
    const float* y0    = (const float*)d_in[0];
    const float* U     = (const float*)d_in[1];
    const float* lre   = (const float*)d_in[2];
    const float* lim   = (const float*)d_in[3];
    const float* B     = (const float*)d_in[4];
    const float* W_y2x = (const float*)d_in[5];
    const float* b_y2x = (const float*)d_in[6];
    const float* W_x2y = (const float*)d_in[7];
    const float* b_x2y = (const float*)d_in[8];
    float* Y = (float*)d_out;

    char* p = (char*)d_ws;
    float2* E        = (float2*)p; p += (size_t)CCH * 4096 * sizeof(float2);   // 16.8 MB
    float2* Carry    = (float2*)p; p += (size_t)CCH * 4096 * sizeof(float2);   // 16.8 MB
    float2* Esup     = (float2*)p; p += (size_t)SEGN * 4096 * sizeof(float2);  // 512 KB
    float2* x0p      = (float2*)p; p += (size_t)4096 * sizeof(float2);         // 32 KB
    unsigned short* Bph = (unsigned short*)p; p += 16384 * sizeof(unsigned short);
    unsigned short* Bpl = (unsigned short*)p; p += 16384 * sizeof(unsigned short);
    unsigned short* Wph = (unsigned short*)p; p += 16384 * sizeof(unsigned short);
    unsigned short* Wpl = (unsigned short*)p; p += 16384 * sizeof(unsigned short);

    k_prep <<<dim3(96),  dim3(256), 0, stream>>>(B, W_x2y, y0, W_y2x, b_y2x, Bph, Bpl, Wph, Wpl, x0p);
    k_pass1<<<dim3(CCH), dim3(256), 0, stream>>>(U, Bph, Bpl, lre, lim, E);
    k_cseg <<<dim3(256), dim3(256), 0, stream>>>(lre, lim, E, Esup);
    k_cexp2<<<dim3(256), dim3(256), 0, stream>>>(lre, lim, x0p, Esup, E, Carry);
    k_pass2<<<dim3(CCH), dim3(256), 0, stream>>>(U, Bph, Bpl, Wph, Wpl, lre, lim, b_x2y, Carry, Y);
}